// Round 19
// baseline (223.639 us; speedup 1.0000x reference)
//
#include <hip/hip_runtime.h>

#define N_NODES 50000
#define N_EDGES 600000
#define N_REL 8
#define NT_PAD 50176      // 196 * 256
#define N_TILES 196
#define NBLK 782          // ceil(50000/64)

typedef __attribute__((ext_vector_type(8))) short bf16x8;
typedef __attribute__((ext_vector_type(4))) float f32x4;

__device__ __forceinline__ ushort f2b(float f) {
    union { float f; unsigned u; } v; v.f = f;
    unsigned r = v.u + 0x7FFFu + ((v.u >> 16) & 1u);
    return (ushort)(r >> 16);
}
__device__ __forceinline__ float b2f(ushort s) {
    union { unsigned u; float f; } v; v.u = ((unsigned)s) << 16;
    return v.f;
}
__device__ __forceinline__ float asf(unsigned u) {
    union { unsigned u; float f; } v; v.u = u;
    return v.f;
}

// ---------------- converts / weight prep ----------------

__global__ void conv_f32_bf16(const float* __restrict__ in, ushort* __restrict__ outb) {
    int i = (blockIdx.x * 256 + threadIdx.x) * 4;
    float4 f = *(const float4*)(in + i);
    ushort4 o; o.x = f2b(f.x); o.y = f2b(f.y); o.z = f2b(f.z); o.w = f2b(f.w);
    *(ushort4*)(outb + i) = o;
}

// wst [128 cols][1152 k] = stack(Wrel[0..7], Wloop)^T ; w1t [256][256]; w2t [128][256]
__global__ void transpose_wts3(const float* __restrict__ Wloop, const float* __restrict__ Wrel,
                               const float* __restrict__ W1, const float* __restrict__ W2,
                               ushort* __restrict__ wt) {
    int y = blockIdx.y;
    if (y == 0) {
        for (int idx = blockIdx.x * 256 + threadIdx.x; idx < 128 * 1152; idx += gridDim.x * 256) {
            int c = idx / 1152, kg = idx - c * 1152;
            float v = (kg < 1024) ? Wrel[(size_t)((kg >> 7) * 128 + (kg & 127)) * 128 + c]
                                  : Wloop[(size_t)(kg - 1024) * 128 + c];
            wt[idx] = f2b(v);
        }
    } else if (y == 1) {
        for (int idx = blockIdx.x * 256 + threadIdx.x; idx < 256 * 256; idx += gridDim.x * 256) {
            int c = idx >> 8, k = idx & 255;
            wt[147456 + idx] = f2b(W1[k * 256 + c]);
        }
    } else {
        for (int idx = blockIdx.x * 256 + threadIdx.x; idx < 128 * 256; idx += gridDim.x * 256) {
            int c = idx >> 8, k = idx & 255;
            wt[212992 + idx] = f2b(W2[k * 128 + c]);
        }
    }
}

// ---------------- MFMA GEMM: 64x128 tile, 4 waves, BK=64, dbuf + A-prefetch ----------------
// KMODE 0 (NPH=18): p<16 reads fragment-major aggF (fully coalesced, lane*16B);
//                   p>=16 reads A1 + (p-16)*64 (row-major xbf, stride 128).
// OMODE 4: bf16 out+bias, width 128.
template<int NPH, int KMODE, int AS, int CTOT, int OMODE>
__global__ __launch_bounds__(256, 4) void mfma_gemm(
        const ushort* __restrict__ A0, const ushort* __restrict__ A1,
        const ushort* __restrict__ Bt, const float* __restrict__ bias,
        void* __restrict__ outv) {
    __shared__ ushort bs[2][128 * 72];
    const int t = threadIdx.x;
    const int wave = t >> 6, lane = t & 63;
    const int lr = lane & 15, lg = lane >> 4;
    const int wr = (wave >> 1) * 32, wc = (wave & 1) * 64;
    const int row0 = blockIdx.x * 64;
    const int KTOT = NPH * 64;
    const ushort* Btb = Bt + (size_t)blockIdx.y * 128 * KTOT;
    const int sgk = (t & 7) * 8;
    const int sc0 = t >> 3;

#define STAGE_LOAD(p)                                                              \
    _Pragma("unroll")                                                              \
    for (int it = 0; it < 4; ++it)                                                 \
        sreg[it] = *(const bf16x8*)(Btb + (size_t)(sc0 + it * 32) * KTOT +         \
                                    (p) * 64 + sgk);

#define STAGE_WRITE(b)                                                             \
    _Pragma("unroll")                                                              \
    for (int it = 0; it < 4; ++it)                                                 \
        *(bf16x8*)(&bs[b][(sc0 + it * 32) * 72 + sgk]) = sreg[it];

#define LOAD_AF(p, dstf)                                                           \
    {                                                                              \
        if (KMODE == 0 && (p) < 16) {                                              \
            _Pragma("unroll")                                                      \
            for (int rt = 0; rt < 2; ++rt)                                         \
                _Pragma("unroll")                                                  \
                for (int kc = 0; kc < 2; ++kc)                                     \
                    dstf[rt][kc] = *(const bf16x8*)(A0 +                           \
                        ((((((size_t)blockIdx.x * 16 + (p)) * 2 + (wave >> 1))     \
                           * 2 + rt) * 2 + kc) * 64 + lane) * 8);                  \
        } else {                                                                   \
            const ushort* Ap; int as_;                                             \
            if (KMODE == 0) { Ap = A1 + ((p) - 16) * 64; as_ = 128; }              \
            else            { Ap = A0 + (p) * 64;        as_ = AS;  }              \
            _Pragma("unroll")                                                      \
            for (int rt = 0; rt < 2; ++rt) {                                       \
                int ar = row0 + wr + rt * 16 + lr;                                 \
                if (ar >= N_NODES) ar = 0;                                         \
                _Pragma("unroll")                                                  \
                for (int kc = 0; kc < 2; ++kc)                                     \
                    dstf[rt][kc] = *(const bf16x8*)(Ap + (size_t)ar * as_ + kc * 32 + lg * 8); \
            }                                                                      \
        }                                                                          \
    }

    f32x4 acc[2][4];
#pragma unroll
    for (int rt = 0; rt < 2; ++rt)
#pragma unroll
        for (int nt = 0; nt < 4; ++nt) acc[rt][nt] = (f32x4){0.f, 0.f, 0.f, 0.f};

    bf16x8 af[2][2], afn[2][2], sreg[4];

    STAGE_LOAD(0);
    LOAD_AF(0, af);
    STAGE_WRITE(0);
    __syncthreads();

#pragma unroll
    for (int p = 0; p < NPH; ++p) {
        if (p + 1 < NPH) {
            STAGE_LOAD(p + 1);
            LOAD_AF(p + 1, afn);
        }
        const ushort* bcur = bs[p & 1];
#pragma unroll
        for (int kc = 0; kc < 2; ++kc) {
            bf16x8 bf[4];
#pragma unroll
            for (int nt = 0; nt < 4; ++nt)
                bf[nt] = *(const bf16x8*)(bcur + (wc + nt * 16 + lr) * 72 + kc * 32 + lg * 8);
#pragma unroll
            for (int rt = 0; rt < 2; ++rt)
#pragma unroll
                for (int nt = 0; nt < 4; ++nt)
                    acc[rt][nt] = __builtin_amdgcn_mfma_f32_16x16x32_bf16(af[rt][kc], bf[nt], acc[rt][nt], 0, 0, 0);
        }
        if (p + 1 < NPH) STAGE_WRITE((p + 1) & 1);
        __syncthreads();
        if (p + 1 < NPH) {
#pragma unroll
            for (int rt = 0; rt < 2; ++rt)
#pragma unroll
                for (int kc = 0; kc < 2; ++kc) af[rt][kc] = afn[rt][kc];
        }
    }

    const int colbase = blockIdx.y * 128;
#pragma unroll
    for (int rt = 0; rt < 2; ++rt) {
#pragma unroll
        for (int nt = 0; nt < 4; ++nt) {
            const int col = colbase + wc + nt * 16 + lr;
            const float bv = bias[col];
#pragma unroll
            for (int j = 0; j < 4; ++j) {
                const int r = row0 + wr + rt * 16 + lg * 4 + j;
                if (r >= N_NODES) continue;
                float vv = acc[rt][nt][j] + bv;
                if (OMODE == 0) {
                    ((float*)outv)[(size_t)r * CTOT + col] = vv;
                } else { // OMODE 4
                    ((ushort*)outv)[(size_t)r * 128 + col] = f2b(vv);
                }
            }
        }
    }
#undef STAGE_LOAD
#undef STAGE_WRITE
#undef LOAD_AF
}

// ---------------- fused MLP (r18 proven): h in LDS ----------------
__global__ __launch_bounds__(256, 2) void mlp_fused(
        const ushort* __restrict__ xbf, const ushort* __restrict__ midbf,
        const ushort* __restrict__ w1t, const ushort* __restrict__ w2t,
        const float* __restrict__ b1, const float* __restrict__ b2,
        float* __restrict__ out) {
    __shared__ ushort ldsA[256 * 72];
    __shared__ ushort ldsB[256 * 72];
    const int t = threadIdx.x;
    const int wave = t >> 6, lane = t & 63;
    const int lr = lane & 15, lg = lane >> 4;
    const int row0 = blockIdx.x * 64;
    const int sgk = (t & 7) * 8;
    const int sc0 = t >> 3;

    // ======== stage 1 ========
    {
        const int wr = (wave >> 1) * 32, wc = (wave & 1) * 128;
        f32x4 acc[2][8];
#pragma unroll
        for (int rt = 0; rt < 2; ++rt)
#pragma unroll
            for (int nt = 0; nt < 8; ++nt) acc[rt][nt] = (f32x4){0.f, 0.f, 0.f, 0.f};
        bf16x8 af[2][2], afn[2][2], sreg[8];

#define S1_LOAD(p)                                                                 \
    _Pragma("unroll")                                                              \
    for (int it = 0; it < 8; ++it)                                                 \
        sreg[it] = *(const bf16x8*)(w1t + (size_t)(sc0 + it * 32) * 256 + (p) * 64 + sgk);

#define S1_WRITE(bptr)                                                             \
    _Pragma("unroll")                                                              \
    for (int it = 0; it < 8; ++it)                                                 \
        *(bf16x8*)((bptr) + (sc0 + it * 32) * 72 + sgk) = sreg[it];

#define S1_AF(p, dstf)                                                             \
    {                                                                              \
        const ushort* Ap = ((p) < 2) ? (xbf + (p) * 64) : (midbf + ((p) - 2) * 64);\
        _Pragma("unroll")                                                          \
        for (int rt = 0; rt < 2; ++rt) {                                           \
            int ar = row0 + wr + rt * 16 + lr;                                     \
            if (ar >= N_NODES) ar = 0;                                             \
            _Pragma("unroll")                                                      \
            for (int kc = 0; kc < 2; ++kc)                                         \
                dstf[rt][kc] = *(const bf16x8*)(Ap + (size_t)ar * 128 + kc * 32 + lg * 8); \
        }                                                                          \
    }

        S1_LOAD(0); S1_AF(0, af); S1_WRITE(ldsA);
        __syncthreads();
#pragma unroll
        for (int p = 0; p < 4; ++p) {
            if (p < 3) { S1_LOAD(p + 1); S1_AF(p + 1, afn); }
            const ushort* bc = (p & 1) ? ldsB : ldsA;
#pragma unroll
            for (int kc = 0; kc < 2; ++kc) {
                bf16x8 bf[8];
#pragma unroll
                for (int nt = 0; nt < 8; ++nt)
                    bf[nt] = *(const bf16x8*)(bc + (wc + nt * 16 + lr) * 72 + kc * 32 + lg * 8);
#pragma unroll
                for (int rt = 0; rt < 2; ++rt)
#pragma unroll
                    for (int nt = 0; nt < 8; ++nt)
                        acc[rt][nt] = __builtin_amdgcn_mfma_f32_16x16x32_bf16(af[rt][kc], bf[nt], acc[rt][nt], 0, 0, 0);
            }
            if (p < 3) { S1_WRITE(((p + 1) & 1) ? ldsB : ldsA); }
            __syncthreads();
            if (p < 3) {
#pragma unroll
                for (int rt = 0; rt < 2; ++rt)
#pragma unroll
                    for (int kc = 0; kc < 2; ++kc) af[rt][kc] = afn[rt][kc];
            }
        }
#pragma unroll
        for (int rt = 0; rt < 2; ++rt)
#pragma unroll
            for (int nt = 0; nt < 8; ++nt) {
                const int col = wc + nt * 16 + lr;
                const float bv = b1[col];
#pragma unroll
                for (int j = 0; j < 4; ++j) {
                    const int hr = wr + rt * 16 + lg * 4 + j;
                    ldsA[hr * 264 + col] = f2b(fmaxf(acc[rt][nt][j] + bv, 0.f));
                }
            }
#undef S1_LOAD
#undef S1_WRITE
#undef S1_AF
    }

    // ======== stage 2 ========
    {
        bf16x8 sreg2[4];
#define S2_LOAD(p)                                                                 \
    _Pragma("unroll")                                                              \
    for (int it = 0; it < 4; ++it)                                                 \
        sreg2[it] = *(const bf16x8*)(w2t + (size_t)(sc0 + it * 32) * 256 + (p) * 64 + sgk);

#define S2_WRITE(half)                                                             \
    _Pragma("unroll")                                                              \
    for (int it = 0; it < 4; ++it)                                                 \
        *(bf16x8*)(ldsB + (half) * (128 * 72) + (sc0 + it * 32) * 72 + sgk) = sreg2[it];

        S2_LOAD(0); S2_WRITE(0);
        __syncthreads();

        const int wr = (wave >> 1) * 32, wc = (wave & 1) * 64;
        f32x4 acc[2][4];
#pragma unroll
        for (int rt = 0; rt < 2; ++rt)
#pragma unroll
            for (int nt = 0; nt < 4; ++nt) acc[rt][nt] = (f32x4){0.f, 0.f, 0.f, 0.f};
        bf16x8 af[2][2];

#pragma unroll
        for (int p = 0; p < 4; ++p) {
            if (p < 3) S2_LOAD(p + 1);
#pragma unroll
            for (int rt = 0; rt < 2; ++rt) {
                const int ar = wr + rt * 16 + lr;
#pragma unroll
                for (int kc = 0; kc < 2; ++kc)
                    af[rt][kc] = *(const bf16x8*)(ldsA + ar * 264 + p * 64 + kc * 32 + lg * 8);
            }
            const ushort* bc = ldsB + (p & 1) * (128 * 72);
#pragma unroll
            for (int kc = 0; kc < 2; ++kc) {
                bf16x8 bf[4];
#pragma unroll
                for (int nt = 0; nt < 4; ++nt)
                    bf[nt] = *(const bf16x8*)(bc + (wc + nt * 16 + lr) * 72 + kc * 32 + lg * 8);
#pragma unroll
                for (int rt = 0; rt < 2; ++rt)
#pragma unroll
                    for (int nt = 0; nt < 4; ++nt)
                        acc[rt][nt] = __builtin_amdgcn_mfma_f32_16x16x32_bf16(af[rt][kc], bf[nt], acc[rt][nt], 0, 0, 0);
            }
            if (p < 3) S2_WRITE((p + 1) & 1);
            __syncthreads();
        }
#pragma unroll
        for (int rt = 0; rt < 2; ++rt)
#pragma unroll
            for (int nt = 0; nt < 4; ++nt) {
                const int col = wc + nt * 16 + lr;
                const float bv = b2[col];
#pragma unroll
                for (int j = 0; j < 4; ++j) {
                    const int r = row0 + wr + rt * 16 + lg * 4 + j;
                    if (r < N_NODES)
                        out[(size_t)r * 128 + col] = acc[rt][nt][j] + bv;
                }
            }
#undef S2_LOAD
#undef S2_WRITE
    }
}

// ---------------- CSR build (counting sort by dst) ----------------

__global__ void zero_cnt(int* __restrict__ cnt) {
    int i = blockIdx.x * 256 + threadIdx.x;
    if (i < NT_PAD) cnt[i] = 0;
}

__global__ void hist_dst(const int* __restrict__ dst, int* __restrict__ cnt) {
    int e = blockIdx.x * 256 + threadIdx.x;
    if (e < N_EDGES) atomicAdd(&cnt[dst[e]], 1);
}

__global__ void scan_tiles(const int* __restrict__ cnt, int* __restrict__ tincl, int* __restrict__ bsum) {
    __shared__ int s[256];
    int i = blockIdx.x * 256 + threadIdx.x;
    int v = cnt[i];
    s[threadIdx.x] = v;
    __syncthreads();
    for (int off = 1; off < 256; off <<= 1) {
        int add = (threadIdx.x >= off) ? s[threadIdx.x - off] : 0;
        __syncthreads();
        s[threadIdx.x] += add;
        __syncthreads();
    }
    tincl[i] = s[threadIdx.x];
    if (threadIdx.x == 255) bsum[blockIdx.x] = s[255];
}

__global__ void scan_bsum(const int* __restrict__ bsum, int* __restrict__ bex) {
    __shared__ int s[256];
    int v = (threadIdx.x < N_TILES) ? bsum[threadIdx.x] : 0;
    s[threadIdx.x] = v;
    __syncthreads();
    for (int off = 1; off < 256; off <<= 1) {
        int add = (threadIdx.x >= off) ? s[threadIdx.x - off] : 0;
        __syncthreads();
        s[threadIdx.x] += add;
        __syncthreads();
    }
    if (threadIdx.x < N_TILES) bex[threadIdx.x] = s[threadIdx.x] - v;
}

__global__ void finalize_base(const int* __restrict__ cnt, const int* __restrict__ tincl,
                              const int* __restrict__ bex, int* __restrict__ base,
                              int* __restrict__ cursor) {
    int i = blockIdx.x * 256 + threadIdx.x;
    int b = tincl[i] - cnt[i] + bex[blockIdx.x];
    base[i] = b; cursor[i] = b;
}

__global__ void scatter_ids(const int* __restrict__ src, const int* __restrict__ dst,
                            const int* __restrict__ et, int* __restrict__ cursor,
                            unsigned* __restrict__ sorted) {
    int e = blockIdx.x * 256 + threadIdx.x;
    if (e >= N_EDGES) return;
    int pos = atomicAdd(&cursor[dst[e]], 1);
    sorted[pos] = ((unsigned)src[e] << 3) | (unsigned)et[e];
}

// ---------------- gather_agg: fragment-major output ----------------
// Accumulation identical to r14 (scalar bases + real branch chain); only the final
// write targets aggF[b][p][half][rt][kc][lane][8] so the GEMM A-reads coalesce.

#define ACC_ADD(sd, v)                                                       \
    {                                                                        \
        float lo = asf((v) << 16);                                           \
        float hi = asf((v) & 0xffff0000u);                                   \
        switch ((sd) & 7u) {                                                 \
            case 0: a0[0] += lo; a1[0] += hi; asm volatile(""); break;       \
            case 1: a0[1] += lo; a1[1] += hi; asm volatile(""); break;       \
            case 2: a0[2] += lo; a1[2] += hi; asm volatile(""); break;       \
            case 3: a0[3] += lo; a1[3] += hi; asm volatile(""); break;       \
            case 4: a0[4] += lo; a1[4] += hi; asm volatile(""); break;       \
            case 5: a0[5] += lo; a1[5] += hi; asm volatile(""); break;       \
            case 6: a0[6] += lo; a1[6] += hi; asm volatile(""); break;       \
            default: a0[7] += lo; a1[7] += hi; asm volatile(""); break;      \
        }                                                                    \
    }

__global__ __launch_bounds__(256) void gather_agg(
        const unsigned* __restrict__ sorted, const int* __restrict__ base,
        const int* __restrict__ cnt, const ushort* __restrict__ xbf,
        ushort* __restrict__ aggF) {
    const int w = threadIdx.x >> 6, lane = threadIdx.x & 63;
    const int n = blockIdx.x * 4 + w;
    const int b = base[n], c = cnt[n];
    const int loff = lane * 2;

    float a0[8], a1[8];
#pragma unroll
    for (int r = 0; r < 8; ++r) { a0[r] = 0.f; a1[r] = 0.f; }

    const unsigned* sp = sorted + b;
    int i = 0;
    for (; i + 4 <= c; i += 4) {
        unsigned s0 = __builtin_amdgcn_readfirstlane(sp[i]);
        unsigned s1 = __builtin_amdgcn_readfirstlane(sp[i + 1]);
        unsigned s2 = __builtin_amdgcn_readfirstlane(sp[i + 2]);
        unsigned s3 = __builtin_amdgcn_readfirstlane(sp[i + 3]);
        unsigned v0 = *(const unsigned*)(xbf + ((size_t)(s0 >> 3) << 7) + loff);
        unsigned v1 = *(const unsigned*)(xbf + ((size_t)(s1 >> 3) << 7) + loff);
        unsigned v2 = *(const unsigned*)(xbf + ((size_t)(s2 >> 3) << 7) + loff);
        unsigned v3 = *(const unsigned*)(xbf + ((size_t)(s3 >> 3) << 7) + loff);
        ACC_ADD(s0, v0); ACC_ADD(s1, v1); ACC_ADD(s2, v2); ACC_ADD(s3, v3);
    }
    for (; i < c; ++i) {
        unsigned sd = __builtin_amdgcn_readfirstlane(sp[i]);
        unsigned v = *(const unsigned*)(xbf + ((size_t)(sd >> 3) << 7) + loff);
        ACC_ADD(sd, v);
    }

    // fragment-major write: n -> (bq, half, rt, lrw); lane L holds k=r*128+2L ->
    // p = r*2 + (L>>5), kc = (L>>4)&1, lg = (L>>2)&3, e = (L&3)*2, frag_lane = lg*16+lrw
    const int bq = n >> 6, q = n & 63;
    const int half = q >> 5, rt = (q >> 4) & 1, lrw = q & 15;
    const int kcw = (lane >> 4) & 1, lgw = (lane >> 2) & 3, ew = (lane & 3) * 2;
    const int flane = lgw * 16 + lrw;
    const int phi = lane >> 5;
#pragma unroll
    for (int r = 0; r < 8; ++r) {
        const int p = r * 2 + phi;
        size_t idx = ((((((size_t)bq * 16 + p) * 2 + half) * 2 + rt) * 2 + kcw) * 64 + flane) * 8 + ew;
        unsigned pk = (unsigned)f2b(a0[r]) | ((unsigned)f2b(a1[r]) << 16);
        *(unsigned*)(aggF + idx) = pk;
    }
}
#undef ACC_ADD

// ---------------- launch ----------------

extern "C" void kernel_launch(void* const* d_in, const int* in_sizes, int n_in,
                              void* d_out, int out_size, void* d_ws, size_t ws_size,
                              hipStream_t stream) {
    const float* x     = (const float*)d_in[0];
    const int*   src   = (const int*)  d_in[1];
    const int*   dst   = (const int*)  d_in[2];
    const int*   etype = (const int*)  d_in[3];
    const float* Wrel  = (const float*)d_in[4];
    const float* Wloop = (const float*)d_in[5];
    const float* brel  = (const float*)d_in[6];
    const float* W1    = (const float*)d_in[7];
    const float* b1    = (const float*)d_in[8];
    const float* W2    = (const float*)d_in[9];
    const float* b2    = (const float*)d_in[10];
    float* out = (float*)d_out;

    // ws layout — total 131,794,688 B (ws_size = 256 MiB, confirmed round 7/8).
    char* ws = (char*)d_ws;
    ushort* aggF  = (ushort*)ws;                     // 102,498,304 B  [782][16][2][2][2][64][8] bf16
    ushort* wt    = (ushort*)(ws + 102498304);       //     491,520 B  wst/w1t/w2t
    char* meta    = ws + 102989824;
    int* cnt      = (int*)(meta);                    // 200,704 B
    int* base     = (int*)(meta + 200704);           // 200,704 B
    int* cursor   = (int*)(meta + 401408);           // 200,704 B
    int* tincl    = (int*)(meta + 602112);           // 200,704 B
    int* bsum     = (int*)(meta + 802816);           //   1,024 B
    int* bex      = (int*)(meta + 803840);           //   1,024 B
    unsigned* sorted = (unsigned*)(meta + 804864);   // 2,400,000 B  (meta end 106,194,688)
    ushort* xbf   = (ushort*)(ws + 106194688);       // 12,800,000 B  bf16(x)
    ushort* midbf = (ushort*)(ws + 118994688);       // 12,800,000 B  bf16(mid)  (end 131,794,688)

    const ushort* wst = wt;              // [128][1152]  stack(Wrel, Wloop)^T
    const ushort* w1t = wt + 147456;     // [256][256]
    const ushort* w2t = wt + 212992;     // [128][256]

    conv_f32_bf16<<<6250, 256, 0, stream>>>(x, xbf);
    transpose_wts3<<<dim3(64, 3), 256, 0, stream>>>(Wloop, Wrel, W1, W2, wt);

    // CSR build (counting sort of edges by dst)
    zero_cnt<<<N_TILES, 256, 0, stream>>>(cnt);
    hist_dst<<<(N_EDGES + 255) / 256, 256, 0, stream>>>(dst, cnt);
    scan_tiles<<<N_TILES, 256, 0, stream>>>(cnt, tincl, bsum);
    scan_bsum<<<1, 256, 0, stream>>>(bsum, bex);
    finalize_base<<<N_TILES, 256, 0, stream>>>(cnt, tincl, bex, base, cursor);
    scatter_ids<<<(N_EDGES + 255) / 256, 256, 0, stream>>>(src, dst, etype, cursor, sorted);

    // aggF[b][p][...] = fragment-major sum of x[src] over edges (dst, etype)
    gather_agg<<<N_NODES / 4, 256, 0, stream>>>(sorted, base, cnt, xbf, aggF);

    // midbf = bf16( concat(agg, x) @ stack(Wrel, Wloop) + brel )  (K=1152, 18 phases, coalesced A)
    mfma_gemm<18, 0, 0, 128, 4><<<dim3(NBLK, 1), 256, 0, stream>>>(aggF, xbf, wst, brel, (void*)midbf);

    // out = relu(concat(x, mid) @ W1 + b1) @ W2 + b2   (fused, h in LDS)
    mlp_fused<<<NBLK, 256, 0, stream>>>(xbf, midbf, w1t, w2t, b1, b2, out);
}

// Round 20
// 221.301 us; speedup vs baseline: 1.0106x; 1.0106x over previous
//
#include <hip/hip_runtime.h>

#define N_NODES 50000
#define N_EDGES 600000
#define N_REL 8
#define NT_PAD 50176      // 196 * 256
#define N_TILES 196
#define NBLK 782          // ceil(50000/64)

typedef __attribute__((ext_vector_type(8))) short bf16x8;
typedef __attribute__((ext_vector_type(4))) float f32x4;

__device__ __forceinline__ ushort f2b(float f) {
    union { float f; unsigned u; } v; v.f = f;
    unsigned r = v.u + 0x7FFFu + ((v.u >> 16) & 1u);
    return (ushort)(r >> 16);
}
__device__ __forceinline__ float b2f(ushort s) {
    union { unsigned u; float f; } v; v.u = ((unsigned)s) << 16;
    return v.f;
}
__device__ __forceinline__ float asf(unsigned u) {
    union { unsigned u; float f; } v; v.u = u;
    return v.f;
}

// ---------------- converts / weight prep ----------------

__global__ void conv_f32_bf16(const float* __restrict__ in, ushort* __restrict__ outb) {
    int i = (blockIdx.x * 256 + threadIdx.x) * 4;
    float4 f = *(const float4*)(in + i);
    ushort4 o; o.x = f2b(f.x); o.y = f2b(f.y); o.z = f2b(f.z); o.w = f2b(f.w);
    *(ushort4*)(outb + i) = o;
}

// wst [128 cols][1152 k] = stack(Wrel[0..7], Wloop)^T ; w1t [256][256]; w2t [128][256]
__global__ void transpose_wts3(const float* __restrict__ Wloop, const float* __restrict__ Wrel,
                               const float* __restrict__ W1, const float* __restrict__ W2,
                               ushort* __restrict__ wt) {
    int y = blockIdx.y;
    if (y == 0) {
        for (int idx = blockIdx.x * 256 + threadIdx.x; idx < 128 * 1152; idx += gridDim.x * 256) {
            int c = idx / 1152, kg = idx - c * 1152;
            float v = (kg < 1024) ? Wrel[(size_t)((kg >> 7) * 128 + (kg & 127)) * 128 + c]
                                  : Wloop[(size_t)(kg - 1024) * 128 + c];
            wt[idx] = f2b(v);
        }
    } else if (y == 1) {
        for (int idx = blockIdx.x * 256 + threadIdx.x; idx < 256 * 256; idx += gridDim.x * 256) {
            int c = idx >> 8, k = idx & 255;
            wt[147456 + idx] = f2b(W1[k * 256 + c]);
        }
    } else {
        for (int idx = blockIdx.x * 256 + threadIdx.x; idx < 128 * 256; idx += gridDim.x * 256) {
            int c = idx >> 8, k = idx & 255;
            wt[212992 + idx] = f2b(W2[k * 128 + c]);
        }
    }
}

// ---------------- MFMA GEMM (r19): 64x128 tile, BK=64, dbuf + A-prefetch, frag-major A ----------------
// KMODE 0 (NPH=18): p<16 reads fragment-major aggF (fully coalesced, lane*16B);
//                   p>=16 reads A1 + (p-16)*64 (row-major xbf, stride 128).
// OMODE 4: bf16 out+bias, width 128.
template<int NPH, int KMODE, int AS, int CTOT, int OMODE>
__global__ __launch_bounds__(256, 4) void mfma_gemm(
        const ushort* __restrict__ A0, const ushort* __restrict__ A1,
        const ushort* __restrict__ Bt, const float* __restrict__ bias,
        void* __restrict__ outv) {
    __shared__ ushort bs[2][128 * 72];
    const int t = threadIdx.x;
    const int wave = t >> 6, lane = t & 63;
    const int lr = lane & 15, lg = lane >> 4;
    const int wr = (wave >> 1) * 32, wc = (wave & 1) * 64;
    const int row0 = blockIdx.x * 64;
    const int KTOT = NPH * 64;
    const ushort* Btb = Bt + (size_t)blockIdx.y * 128 * KTOT;
    const int sgk = (t & 7) * 8;
    const int sc0 = t >> 3;

#define STAGE_LOAD(p)                                                              \
    _Pragma("unroll")                                                              \
    for (int it = 0; it < 4; ++it)                                                 \
        sreg[it] = *(const bf16x8*)(Btb + (size_t)(sc0 + it * 32) * KTOT +         \
                                    (p) * 64 + sgk);

#define STAGE_WRITE(b)                                                             \
    _Pragma("unroll")                                                              \
    for (int it = 0; it < 4; ++it)                                                 \
        *(bf16x8*)(&bs[b][(sc0 + it * 32) * 72 + sgk]) = sreg[it];

#define LOAD_AF(p, dstf)                                                           \
    {                                                                              \
        if (KMODE == 0 && (p) < 16) {                                              \
            _Pragma("unroll")                                                      \
            for (int rt = 0; rt < 2; ++rt)                                         \
                _Pragma("unroll")                                                  \
                for (int kc = 0; kc < 2; ++kc)                                     \
                    dstf[rt][kc] = *(const bf16x8*)(A0 +                           \
                        ((((((size_t)blockIdx.x * 16 + (p)) * 2 + (wave >> 1))     \
                           * 2 + rt) * 2 + kc) * 64 + lane) * 8);                  \
        } else {                                                                   \
            const ushort* Ap; int as_;                                             \
            if (KMODE == 0) { Ap = A1 + ((p) - 16) * 64; as_ = 128; }              \
            else            { Ap = A0 + (p) * 64;        as_ = AS;  }              \
            _Pragma("unroll")                                                      \
            for (int rt = 0; rt < 2; ++rt) {                                       \
                int ar = row0 + wr + rt * 16 + lr;                                 \
                if (ar >= N_NODES) ar = 0;                                         \
                _Pragma("unroll")                                                  \
                for (int kc = 0; kc < 2; ++kc)                                     \
                    dstf[rt][kc] = *(const bf16x8*)(Ap + (size_t)ar * as_ + kc * 32 + lg * 8); \
            }                                                                      \
        }                                                                          \
    }

    f32x4 acc[2][4];
#pragma unroll
    for (int rt = 0; rt < 2; ++rt)
#pragma unroll
        for (int nt = 0; nt < 4; ++nt) acc[rt][nt] = (f32x4){0.f, 0.f, 0.f, 0.f};

    bf16x8 af[2][2], afn[2][2], sreg[4];

    STAGE_LOAD(0);
    LOAD_AF(0, af);
    STAGE_WRITE(0);
    __syncthreads();

#pragma unroll
    for (int p = 0; p < NPH; ++p) {
        if (p + 1 < NPH) {
            STAGE_LOAD(p + 1);
            LOAD_AF(p + 1, afn);
        }
        const ushort* bcur = bs[p & 1];
#pragma unroll
        for (int kc = 0; kc < 2; ++kc) {
            bf16x8 bf[4];
#pragma unroll
            for (int nt = 0; nt < 4; ++nt)
                bf[nt] = *(const bf16x8*)(bcur + (wc + nt * 16 + lr) * 72 + kc * 32 + lg * 8);
#pragma unroll
            for (int rt = 0; rt < 2; ++rt)
#pragma unroll
                for (int nt = 0; nt < 4; ++nt)
                    acc[rt][nt] = __builtin_amdgcn_mfma_f32_16x16x32_bf16(af[rt][kc], bf[nt], acc[rt][nt], 0, 0, 0);
        }
        if (p + 1 < NPH) STAGE_WRITE((p + 1) & 1);
        __syncthreads();
        if (p + 1 < NPH) {
#pragma unroll
            for (int rt = 0; rt < 2; ++rt)
#pragma unroll
                for (int kc = 0; kc < 2; ++kc) af[rt][kc] = afn[rt][kc];
        }
    }

    const int colbase = blockIdx.y * 128;
#pragma unroll
    for (int rt = 0; rt < 2; ++rt) {
#pragma unroll
        for (int nt = 0; nt < 4; ++nt) {
            const int col = colbase + wc + nt * 16 + lr;
            const float bv = bias[col];
#pragma unroll
            for (int j = 0; j < 4; ++j) {
                const int r = row0 + wr + rt * 16 + lg * 4 + j;
                if (r >= N_NODES) continue;
                float vv = acc[rt][nt][j] + bv;
                if (OMODE == 0) {
                    ((float*)outv)[(size_t)r * CTOT + col] = vv;
                } else { // OMODE 4
                    ((ushort*)outv)[(size_t)r * 128 + col] = f2b(vv);
                }
            }
        }
    }
#undef STAGE_LOAD
#undef STAGE_WRITE
#undef LOAD_AF
}

// ---------------- fused MLP (r18 proven): h in LDS ----------------
__global__ __launch_bounds__(256, 2) void mlp_fused(
        const ushort* __restrict__ xbf, const ushort* __restrict__ midbf,
        const ushort* __restrict__ w1t, const ushort* __restrict__ w2t,
        const float* __restrict__ b1, const float* __restrict__ b2,
        float* __restrict__ out) {
    __shared__ ushort ldsA[256 * 72];
    __shared__ ushort ldsB[256 * 72];
    const int t = threadIdx.x;
    const int wave = t >> 6, lane = t & 63;
    const int lr = lane & 15, lg = lane >> 4;
    const int row0 = blockIdx.x * 64;
    const int sgk = (t & 7) * 8;
    const int sc0 = t >> 3;

    // ======== stage 1 ========
    {
        const int wr = (wave >> 1) * 32, wc = (wave & 1) * 128;
        f32x4 acc[2][8];
#pragma unroll
        for (int rt = 0; rt < 2; ++rt)
#pragma unroll
            for (int nt = 0; nt < 8; ++nt) acc[rt][nt] = (f32x4){0.f, 0.f, 0.f, 0.f};
        bf16x8 af[2][2], afn[2][2], sreg[8];

#define S1_LOAD(p)                                                                 \
    _Pragma("unroll")                                                              \
    for (int it = 0; it < 8; ++it)                                                 \
        sreg[it] = *(const bf16x8*)(w1t + (size_t)(sc0 + it * 32) * 256 + (p) * 64 + sgk);

#define S1_WRITE(bptr)                                                             \
    _Pragma("unroll")                                                              \
    for (int it = 0; it < 8; ++it)                                                 \
        *(bf16x8*)((bptr) + (sc0 + it * 32) * 72 + sgk) = sreg[it];

#define S1_AF(p, dstf)                                                             \
    {                                                                              \
        const ushort* Ap = ((p) < 2) ? (xbf + (p) * 64) : (midbf + ((p) - 2) * 64);\
        _Pragma("unroll")                                                          \
        for (int rt = 0; rt < 2; ++rt) {                                           \
            int ar = row0 + wr + rt * 16 + lr;                                     \
            if (ar >= N_NODES) ar = 0;                                             \
            _Pragma("unroll")                                                      \
            for (int kc = 0; kc < 2; ++kc)                                         \
                dstf[rt][kc] = *(const bf16x8*)(Ap + (size_t)ar * 128 + kc * 32 + lg * 8); \
        }                                                                          \
    }

        S1_LOAD(0); S1_AF(0, af); S1_WRITE(ldsA);
        __syncthreads();
#pragma unroll
        for (int p = 0; p < 4; ++p) {
            if (p < 3) { S1_LOAD(p + 1); S1_AF(p + 1, afn); }
            const ushort* bc = (p & 1) ? ldsB : ldsA;
#pragma unroll
            for (int kc = 0; kc < 2; ++kc) {
                bf16x8 bf[8];
#pragma unroll
                for (int nt = 0; nt < 8; ++nt)
                    bf[nt] = *(const bf16x8*)(bc + (wc + nt * 16 + lr) * 72 + kc * 32 + lg * 8);
#pragma unroll
                for (int rt = 0; rt < 2; ++rt)
#pragma unroll
                    for (int nt = 0; nt < 8; ++nt)
                        acc[rt][nt] = __builtin_amdgcn_mfma_f32_16x16x32_bf16(af[rt][kc], bf[nt], acc[rt][nt], 0, 0, 0);
            }
            if (p < 3) { S1_WRITE(((p + 1) & 1) ? ldsB : ldsA); }
            __syncthreads();
            if (p < 3) {
#pragma unroll
                for (int rt = 0; rt < 2; ++rt)
#pragma unroll
                    for (int kc = 0; kc < 2; ++kc) af[rt][kc] = afn[rt][kc];
            }
        }
#pragma unroll
        for (int rt = 0; rt < 2; ++rt)
#pragma unroll
            for (int nt = 0; nt < 8; ++nt) {
                const int col = wc + nt * 16 + lr;
                const float bv = b1[col];
#pragma unroll
                for (int j = 0; j < 4; ++j) {
                    const int hr = wr + rt * 16 + lg * 4 + j;
                    ldsA[hr * 264 + col] = f2b(fmaxf(acc[rt][nt][j] + bv, 0.f));
                }
            }
#undef S1_LOAD
#undef S1_WRITE
#undef S1_AF
    }

    // ======== stage 2 ========
    {
        bf16x8 sreg2[4];
#define S2_LOAD(p)                                                                 \
    _Pragma("unroll")                                                              \
    for (int it = 0; it < 4; ++it)                                                 \
        sreg2[it] = *(const bf16x8*)(w2t + (size_t)(sc0 + it * 32) * 256 + (p) * 64 + sgk);

#define S2_WRITE(half)                                                             \
    _Pragma("unroll")                                                              \
    for (int it = 0; it < 4; ++it)                                                 \
        *(bf16x8*)(ldsB + (half) * (128 * 72) + (sc0 + it * 32) * 72 + sgk) = sreg2[it];

        S2_LOAD(0); S2_WRITE(0);
        __syncthreads();

        const int wr = (wave >> 1) * 32, wc = (wave & 1) * 64;
        f32x4 acc[2][4];
#pragma unroll
        for (int rt = 0; rt < 2; ++rt)
#pragma unroll
            for (int nt = 0; nt < 4; ++nt) acc[rt][nt] = (f32x4){0.f, 0.f, 0.f, 0.f};
        bf16x8 af[2][2];

#pragma unroll
        for (int p = 0; p < 4; ++p) {
            if (p < 3) S2_LOAD(p + 1);
#pragma unroll
            for (int rt = 0; rt < 2; ++rt) {
                const int ar = wr + rt * 16 + lr;
#pragma unroll
                for (int kc = 0; kc < 2; ++kc)
                    af[rt][kc] = *(const bf16x8*)(ldsA + ar * 264 + p * 64 + kc * 32 + lg * 8);
            }
            const ushort* bc = ldsB + (p & 1) * (128 * 72);
#pragma unroll
            for (int kc = 0; kc < 2; ++kc) {
                bf16x8 bf[4];
#pragma unroll
                for (int nt = 0; nt < 4; ++nt)
                    bf[nt] = *(const bf16x8*)(bc + (wc + nt * 16 + lr) * 72 + kc * 32 + lg * 8);
#pragma unroll
                for (int rt = 0; rt < 2; ++rt)
#pragma unroll
                    for (int nt = 0; nt < 4; ++nt)
                        acc[rt][nt] = __builtin_amdgcn_mfma_f32_16x16x32_bf16(af[rt][kc], bf[nt], acc[rt][nt], 0, 0, 0);
            }
            if (p < 3) S2_WRITE((p + 1) & 1);
            __syncthreads();
        }
#pragma unroll
        for (int rt = 0; rt < 2; ++rt)
#pragma unroll
            for (int nt = 0; nt < 4; ++nt) {
                const int col = wc + nt * 16 + lr;
                const float bv = b2[col];
#pragma unroll
                for (int j = 0; j < 4; ++j) {
                    const int r = row0 + wr + rt * 16 + lg * 4 + j;
                    if (r < N_NODES)
                        out[(size_t)r * 128 + col] = acc[rt][nt][j] + bv;
                }
            }
#undef S2_LOAD
#undef S2_WRITE
    }
}

// ---------------- CSR build (counting sort by dst) ----------------

__global__ void zero_cnt(int* __restrict__ cnt) {
    int i = blockIdx.x * 256 + threadIdx.x;
    if (i < NT_PAD) cnt[i] = 0;
}

__global__ void hist_dst(const int* __restrict__ dst, int* __restrict__ cnt) {
    int e = blockIdx.x * 256 + threadIdx.x;
    if (e < N_EDGES) atomicAdd(&cnt[dst[e]], 1);
}

__global__ void scan_tiles(const int* __restrict__ cnt, int* __restrict__ tincl, int* __restrict__ bsum) {
    __shared__ int s[256];
    int i = blockIdx.x * 256 + threadIdx.x;
    int v = cnt[i];
    s[threadIdx.x] = v;
    __syncthreads();
    for (int off = 1; off < 256; off <<= 1) {
        int add = (threadIdx.x >= off) ? s[threadIdx.x - off] : 0;
        __syncthreads();
        s[threadIdx.x] += add;
        __syncthreads();
    }
    tincl[i] = s[threadIdx.x];
    if (threadIdx.x == 255) bsum[blockIdx.x] = s[255];
}

__global__ void scan_bsum(const int* __restrict__ bsum, int* __restrict__ bex) {
    __shared__ int s[256];
    int v = (threadIdx.x < N_TILES) ? bsum[threadIdx.x] : 0;
    s[threadIdx.x] = v;
    __syncthreads();
    for (int off = 1; off < 256; off <<= 1) {
        int add = (threadIdx.x >= off) ? s[threadIdx.x - off] : 0;
        __syncthreads();
        s[threadIdx.x] += add;
        __syncthreads();
    }
    if (threadIdx.x < N_TILES) bex[threadIdx.x] = s[threadIdx.x] - v;
}

__global__ void finalize_base(const int* __restrict__ cnt, const int* __restrict__ tincl,
                              const int* __restrict__ bex, int* __restrict__ base,
                              int* __restrict__ cursor) {
    int i = blockIdx.x * 256 + threadIdx.x;
    int b = tincl[i] - cnt[i] + bex[blockIdx.x];
    base[i] = b; cursor[i] = b;
}

__global__ void scatter_ids(const int* __restrict__ src, const int* __restrict__ dst,
                            const int* __restrict__ et, int* __restrict__ cursor,
                            unsigned* __restrict__ sorted) {
    int e = blockIdx.x * 256 + threadIdx.x;
    if (e >= N_EDGES) return;
    int pos = atomicAdd(&cursor[dst[e]], 1);
    sorted[pos] = ((unsigned)src[e] << 3) | (unsigned)et[e];
}

// ---------------- gather_agg16: 16 nodes/block, LDS-staged, coalesced frag-major writeout ----------------
// 4 waves x 4 serial nodes (r14-proven scalar-branch accumulation); results staged in
// LDS [16][1032] (pad -> 2-way banks); then 2048 x 16B chunks written with consecutive
// lanes at consecutive addresses (full 1KB bursts) into the fragment-major aggF.

#define ACC_ADD(sd, v)                                                       \
    {                                                                        \
        float lo = asf((v) << 16);                                           \
        float hi = asf((v) & 0xffff0000u);                                   \
        switch ((sd) & 7u) {                                                 \
            case 0: a0[0] += lo; a1[0] += hi; asm volatile(""); break;       \
            case 1: a0[1] += lo; a1[1] += hi; asm volatile(""); break;       \
            case 2: a0[2] += lo; a1[2] += hi; asm volatile(""); break;       \
            case 3: a0[3] += lo; a1[3] += hi; asm volatile(""); break;       \
            case 4: a0[4] += lo; a1[4] += hi; asm volatile(""); break;       \
            case 5: a0[5] += lo; a1[5] += hi; asm volatile(""); break;       \
            case 6: a0[6] += lo; a1[6] += hi; asm volatile(""); break;       \
            default: a0[7] += lo; a1[7] += hi; asm volatile(""); break;      \
        }                                                                    \
    }

__global__ __launch_bounds__(256) void gather_agg16(
        const unsigned* __restrict__ sorted, const int* __restrict__ base,
        const int* __restrict__ cnt, const ushort* __restrict__ xbf,
        ushort* __restrict__ aggF) {
    __shared__ ushort lds[16 * 1032];        // 33,024 B
    const int t = threadIdx.x;
    const int w = t >> 6, lane = t & 63;
    const int ng = blockIdx.x;               // node group: nodes 16*ng .. 16*ng+15
    const int loff = lane * 2;

#pragma unroll
    for (int s = 0; s < 4; ++s) {
        const int nl = w * 4 + s;            // node local 0..15
        const int n = ng * 16 + nl;
        const int b = base[n], c = cnt[n];

        float a0[8], a1[8];
#pragma unroll
        for (int r = 0; r < 8; ++r) { a0[r] = 0.f; a1[r] = 0.f; }

        const unsigned* sp = sorted + b;
        int i = 0;
        for (; i + 4 <= c; i += 4) {
            unsigned s0 = __builtin_amdgcn_readfirstlane(sp[i]);
            unsigned s1 = __builtin_amdgcn_readfirstlane(sp[i + 1]);
            unsigned s2 = __builtin_amdgcn_readfirstlane(sp[i + 2]);
            unsigned s3 = __builtin_amdgcn_readfirstlane(sp[i + 3]);
            unsigned v0 = *(const unsigned*)(xbf + ((size_t)(s0 >> 3) << 7) + loff);
            unsigned v1 = *(const unsigned*)(xbf + ((size_t)(s1 >> 3) << 7) + loff);
            unsigned v2 = *(const unsigned*)(xbf + ((size_t)(s2 >> 3) << 7) + loff);
            unsigned v3 = *(const unsigned*)(xbf + ((size_t)(s3 >> 3) << 7) + loff);
            ACC_ADD(s0, v0); ACC_ADD(s1, v1); ACC_ADD(s2, v2); ACC_ADD(s3, v3);
        }
        for (; i < c; ++i) {
            unsigned sd = __builtin_amdgcn_readfirstlane(sp[i]);
            unsigned v = *(const unsigned*)(xbf + ((size_t)(sd >> 3) << 7) + loff);
            ACC_ADD(sd, v);
        }
        // stage row-major into LDS: lane writes 4B at consecutive addresses (conflict-free)
#pragma unroll
        for (int r = 0; r < 8; ++r) {
            unsigned pk = (unsigned)f2b(a0[r]) | ((unsigned)f2b(a1[r]) << 16);
            *(unsigned*)(lds + nl * 1032 + r * 128 + loff) = pk;
        }
    }
    __syncthreads();

    // coalesced writeout: 2048 chunks of 16B; cid = p*128 + kcw*64 + flane,
    // flane = lgw*16 + nl; LDS read at [nl][p*64 + kcw*32 + lgw*8] (2-way banks).
    const int bq = ng >> 2;
    const int half = (ng & 3) >> 1, rt = ng & 1;
    const size_t obase = ((((size_t)bq * 16) * 2 + half) * 2 + rt) * 2 * 64 * 8; // offset of (bq,p=0,half,rt,kcw=0)
#pragma unroll
    for (int it = 0; it < 8; ++it) {
        int cid = it * 256 + t;
        int flane = cid & 63, kcw = (cid >> 6) & 1, p = cid >> 7;
        int nl = flane & 15, lgw = flane >> 4;
        bf16x8 v = *(const bf16x8*)(lds + nl * 1032 + p * 64 + kcw * 32 + lgw * 8);
        size_t idx = ((((((size_t)bq * 16 + p) * 2 + half) * 2 + rt) * 2 + kcw) * 64 + flane) * 8;
        *(bf16x8*)(aggF + idx) = v;
    }
    (void)obase;
}
#undef ACC_ADD

// ---------------- launch ----------------

extern "C" void kernel_launch(void* const* d_in, const int* in_sizes, int n_in,
                              void* d_out, int out_size, void* d_ws, size_t ws_size,
                              hipStream_t stream) {
    const float* x     = (const float*)d_in[0];
    const int*   src   = (const int*)  d_in[1];
    const int*   dst   = (const int*)  d_in[2];
    const int*   etype = (const int*)  d_in[3];
    const float* Wrel  = (const float*)d_in[4];
    const float* Wloop = (const float*)d_in[5];
    const float* brel  = (const float*)d_in[6];
    const float* W1    = (const float*)d_in[7];
    const float* b1    = (const float*)d_in[8];
    const float* W2    = (const float*)d_in[9];
    const float* b2    = (const float*)d_in[10];
    float* out = (float*)d_out;

    // ws layout — total 131,794,688 B (ws_size = 256 MiB, confirmed round 7/8).
    char* ws = (char*)d_ws;
    ushort* aggF  = (ushort*)ws;                     // 102,498,304 B  [782][16][2][2][2][64][8] bf16
    ushort* wt    = (ushort*)(ws + 102498304);       //     491,520 B  wst/w1t/w2t
    char* meta    = ws + 102989824;
    int* cnt      = (int*)(meta);                    // 200,704 B
    int* base     = (int*)(meta + 200704);           // 200,704 B
    int* cursor   = (int*)(meta + 401408);           // 200,704 B
    int* tincl    = (int*)(meta + 602112);           // 200,704 B
    int* bsum     = (int*)(meta + 802816);           //   1,024 B
    int* bex      = (int*)(meta + 803840);           //   1,024 B
    unsigned* sorted = (unsigned*)(meta + 804864);   // 2,400,000 B  (meta end 106,194,688)
    ushort* xbf   = (ushort*)(ws + 106194688);       // 12,800,000 B  bf16(x)
    ushort* midbf = (ushort*)(ws + 118994688);       // 12,800,000 B  bf16(mid)  (end 131,794,688)

    const ushort* wst = wt;              // [128][1152]  stack(Wrel, Wloop)^T
    const ushort* w1t = wt + 147456;     // [256][256]
    const ushort* w2t = wt + 212992;     // [128][256]

    conv_f32_bf16<<<6250, 256, 0, stream>>>(x, xbf);
    transpose_wts3<<<dim3(64, 3), 256, 0, stream>>>(Wloop, Wrel, W1, W2, wt);

    // CSR build (counting sort of edges by dst)
    zero_cnt<<<N_TILES, 256, 0, stream>>>(cnt);
    hist_dst<<<(N_EDGES + 255) / 256, 256, 0, stream>>>(dst, cnt);
    scan_tiles<<<N_TILES, 256, 0, stream>>>(cnt, tincl, bsum);
    scan_bsum<<<1, 256, 0, stream>>>(bsum, bex);
    finalize_base<<<N_TILES, 256, 0, stream>>>(cnt, tincl, bex, base, cursor);
    scatter_ids<<<(N_EDGES + 255) / 256, 256, 0, stream>>>(src, dst, etype, cursor, sorted);

    // aggF (fragment-major) = sum of x[src] over edges (dst, etype); coalesced writes
    gather_agg16<<<N_NODES / 16, 256, 0, stream>>>(sorted, base, cnt, xbf, aggF);

    // midbf = bf16( concat(agg, x) @ stack(Wrel, Wloop) + brel )  (K=1152, 18 phases, coalesced A)
    mfma_gemm<18, 0, 0, 128, 4><<<dim3(NBLK, 1), 256, 0, stream>>>(aggF, xbf, wst, brel, (void*)midbf);

    // out = relu(concat(x, mid) @ W1 + b1) @ W2 + b2   (fused, h in LDS)
    mlp_fused<<<NBLK, 256, 0, stream>>>(xbf, midbf, w1t, w2t, b1, b2, out);
}

// Round 21
// 195.459 us; speedup vs baseline: 1.1442x; 1.1322x over previous
//
#include <hip/hip_runtime.h>

#define N_NODES 50000
#define N_EDGES 600000
#define N_REL 8
#define NT_PAD 50176      // 196 * 256
#define N_TILES 196
#define NBLK 782          // ceil(50000/64)

typedef __attribute__((ext_vector_type(8))) short bf16x8;
typedef __attribute__((ext_vector_type(4))) float f32x4;

__device__ __forceinline__ ushort f2b(float f) {
    union { float f; unsigned u; } v; v.f = f;
    unsigned r = v.u + 0x7FFFu + ((v.u >> 16) & 1u);
    return (ushort)(r >> 16);
}
__device__ __forceinline__ float b2f(ushort s) {
    union { unsigned u; float f; } v; v.u = ((unsigned)s) << 16;
    return v.f;
}
__device__ __forceinline__ float asf(unsigned u) {
    union { unsigned u; float f; } v; v.u = u;
    return v.f;
}

// ---------------- converts / weight prep ----------------

__global__ void conv_f32_bf16(const float* __restrict__ in, ushort* __restrict__ outb) {
    int i = (blockIdx.x * 256 + threadIdx.x) * 4;
    float4 f = *(const float4*)(in + i);
    ushort4 o; o.x = f2b(f.x); o.y = f2b(f.y); o.z = f2b(f.z); o.w = f2b(f.w);
    *(ushort4*)(outb + i) = o;
}

// wst [128 cols][1152 k] = stack(Wrel[0..7], Wloop)^T ; w1t [256][256]; w2t [128][256]
__global__ void transpose_wts3(const float* __restrict__ Wloop, const float* __restrict__ Wrel,
                               const float* __restrict__ W1, const float* __restrict__ W2,
                               ushort* __restrict__ wt) {
    int y = blockIdx.y;
    if (y == 0) {
        for (int idx = blockIdx.x * 256 + threadIdx.x; idx < 128 * 1152; idx += gridDim.x * 256) {
            int c = idx / 1152, kg = idx - c * 1152;
            float v = (kg < 1024) ? Wrel[(size_t)((kg >> 7) * 128 + (kg & 127)) * 128 + c]
                                  : Wloop[(size_t)(kg - 1024) * 128 + c];
            wt[idx] = f2b(v);
        }
    } else if (y == 1) {
        for (int idx = blockIdx.x * 256 + threadIdx.x; idx < 256 * 256; idx += gridDim.x * 256) {
            int c = idx >> 8, k = idx & 255;
            wt[147456 + idx] = f2b(W1[k * 256 + c]);
        }
    } else {
        for (int idx = blockIdx.x * 256 + threadIdx.x; idx < 128 * 256; idx += gridDim.x * 256) {
            int c = idx >> 8, k = idx & 255;
            wt[212992 + idx] = f2b(W2[k * 128 + c]);
        }
    }
}

// ---------------- MFMA GEMM (r19): 64x128 tile, BK=64, dbuf + A-prefetch, frag-major A ----------------
// KMODE 0 (NPH=18): p<16 reads fragment-major aggF (fully coalesced, lane*16B);
//                   p>=16 reads A1 + (p-16)*64 (row-major xbf, stride 128).
// OMODE 4: bf16 out+bias, width 128.
template<int NPH, int KMODE, int AS, int CTOT, int OMODE>
__global__ __launch_bounds__(256, 4) void mfma_gemm(
        const ushort* __restrict__ A0, const ushort* __restrict__ A1,
        const ushort* __restrict__ Bt, const float* __restrict__ bias,
        void* __restrict__ outv) {
    __shared__ ushort bs[2][128 * 72];
    const int t = threadIdx.x;
    const int wave = t >> 6, lane = t & 63;
    const int lr = lane & 15, lg = lane >> 4;
    const int wr = (wave >> 1) * 32, wc = (wave & 1) * 64;
    const int row0 = blockIdx.x * 64;
    const int KTOT = NPH * 64;
    const ushort* Btb = Bt + (size_t)blockIdx.y * 128 * KTOT;
    const int sgk = (t & 7) * 8;
    const int sc0 = t >> 3;

#define STAGE_LOAD(p)                                                              \
    _Pragma("unroll")                                                              \
    for (int it = 0; it < 4; ++it)                                                 \
        sreg[it] = *(const bf16x8*)(Btb + (size_t)(sc0 + it * 32) * KTOT +         \
                                    (p) * 64 + sgk);

#define STAGE_WRITE(b)                                                             \
    _Pragma("unroll")                                                              \
    for (int it = 0; it < 4; ++it)                                                 \
        *(bf16x8*)(&bs[b][(sc0 + it * 32) * 72 + sgk]) = sreg[it];

#define LOAD_AF(p, dstf)                                                           \
    {                                                                              \
        if (KMODE == 0 && (p) < 16) {                                              \
            _Pragma("unroll")                                                      \
            for (int rt = 0; rt < 2; ++rt)                                         \
                _Pragma("unroll")                                                  \
                for (int kc = 0; kc < 2; ++kc)                                     \
                    dstf[rt][kc] = *(const bf16x8*)(A0 +                           \
                        ((((((size_t)blockIdx.x * 16 + (p)) * 2 + (wave >> 1))     \
                           * 2 + rt) * 2 + kc) * 64 + lane) * 8);                  \
        } else {                                                                   \
            const ushort* Ap; int as_;                                             \
            if (KMODE == 0) { Ap = A1 + ((p) - 16) * 64; as_ = 128; }              \
            else            { Ap = A0 + (p) * 64;        as_ = AS;  }              \
            _Pragma("unroll")                                                      \
            for (int rt = 0; rt < 2; ++rt) {                                       \
                int ar = row0 + wr + rt * 16 + lr;                                 \
                if (ar >= N_NODES) ar = 0;                                         \
                _Pragma("unroll")                                                  \
                for (int kc = 0; kc < 2; ++kc)                                     \
                    dstf[rt][kc] = *(const bf16x8*)(Ap + (size_t)ar * as_ + kc * 32 + lg * 8); \
            }                                                                      \
        }                                                                          \
    }

    f32x4 acc[2][4];
#pragma unroll
    for (int rt = 0; rt < 2; ++rt)
#pragma unroll
        for (int nt = 0; nt < 4; ++nt) acc[rt][nt] = (f32x4){0.f, 0.f, 0.f, 0.f};

    bf16x8 af[2][2], afn[2][2], sreg[4];

    STAGE_LOAD(0);
    LOAD_AF(0, af);
    STAGE_WRITE(0);
    __syncthreads();

#pragma unroll
    for (int p = 0; p < NPH; ++p) {
        if (p + 1 < NPH) {
            STAGE_LOAD(p + 1);
            LOAD_AF(p + 1, afn);
        }
        const ushort* bcur = bs[p & 1];
#pragma unroll
        for (int kc = 0; kc < 2; ++kc) {
            bf16x8 bf[4];
#pragma unroll
            for (int nt = 0; nt < 4; ++nt)
                bf[nt] = *(const bf16x8*)(bcur + (wc + nt * 16 + lr) * 72 + kc * 32 + lg * 8);
#pragma unroll
            for (int rt = 0; rt < 2; ++rt)
#pragma unroll
                for (int nt = 0; nt < 4; ++nt)
                    acc[rt][nt] = __builtin_amdgcn_mfma_f32_16x16x32_bf16(af[rt][kc], bf[nt], acc[rt][nt], 0, 0, 0);
        }
        if (p + 1 < NPH) STAGE_WRITE((p + 1) & 1);
        __syncthreads();
        if (p + 1 < NPH) {
#pragma unroll
            for (int rt = 0; rt < 2; ++rt)
#pragma unroll
                for (int kc = 0; kc < 2; ++kc) af[rt][kc] = afn[rt][kc];
        }
    }

    const int colbase = blockIdx.y * 128;
#pragma unroll
    for (int rt = 0; rt < 2; ++rt) {
#pragma unroll
        for (int nt = 0; nt < 4; ++nt) {
            const int col = colbase + wc + nt * 16 + lr;
            const float bv = bias[col];
#pragma unroll
            for (int j = 0; j < 4; ++j) {
                const int r = row0 + wr + rt * 16 + lg * 4 + j;
                if (r >= N_NODES) continue;
                float vv = acc[rt][nt][j] + bv;
                if (OMODE == 0) {
                    ((float*)outv)[(size_t)r * CTOT + col] = vv;
                } else { // OMODE 4
                    ((ushort*)outv)[(size_t)r * 128 + col] = f2b(vv);
                }
            }
        }
    }
#undef STAGE_LOAD
#undef STAGE_WRITE
#undef LOAD_AF
}

// ---------------- fused MLP (r18 proven): h in LDS ----------------
__global__ __launch_bounds__(256, 2) void mlp_fused(
        const ushort* __restrict__ xbf, const ushort* __restrict__ midbf,
        const ushort* __restrict__ w1t, const ushort* __restrict__ w2t,
        const float* __restrict__ b1, const float* __restrict__ b2,
        float* __restrict__ out) {
    __shared__ ushort ldsA[256 * 72];
    __shared__ ushort ldsB[256 * 72];
    const int t = threadIdx.x;
    const int wave = t >> 6, lane = t & 63;
    const int lr = lane & 15, lg = lane >> 4;
    const int row0 = blockIdx.x * 64;
    const int sgk = (t & 7) * 8;
    const int sc0 = t >> 3;

    // ======== stage 1 ========
    {
        const int wr = (wave >> 1) * 32, wc = (wave & 1) * 128;
        f32x4 acc[2][8];
#pragma unroll
        for (int rt = 0; rt < 2; ++rt)
#pragma unroll
            for (int nt = 0; nt < 8; ++nt) acc[rt][nt] = (f32x4){0.f, 0.f, 0.f, 0.f};
        bf16x8 af[2][2], afn[2][2], sreg[8];

#define S1_LOAD(p)                                                                 \
    _Pragma("unroll")                                                              \
    for (int it = 0; it < 8; ++it)                                                 \
        sreg[it] = *(const bf16x8*)(w1t + (size_t)(sc0 + it * 32) * 256 + (p) * 64 + sgk);

#define S1_WRITE(bptr)                                                             \
    _Pragma("unroll")                                                              \
    for (int it = 0; it < 8; ++it)                                                 \
        *(bf16x8*)((bptr) + (sc0 + it * 32) * 72 + sgk) = sreg[it];

#define S1_AF(p, dstf)                                                             \
    {                                                                              \
        const ushort* Ap = ((p) < 2) ? (xbf + (p) * 64) : (midbf + ((p) - 2) * 64);\
        _Pragma("unroll")                                                          \
        for (int rt = 0; rt < 2; ++rt) {                                           \
            int ar = row0 + wr + rt * 16 + lr;                                     \
            if (ar >= N_NODES) ar = 0;                                             \
            _Pragma("unroll")                                                      \
            for (int kc = 0; kc < 2; ++kc)                                         \
                dstf[rt][kc] = *(const bf16x8*)(Ap + (size_t)ar * 128 + kc * 32 + lg * 8); \
        }                                                                          \
    }

        S1_LOAD(0); S1_AF(0, af); S1_WRITE(ldsA);
        __syncthreads();
#pragma unroll
        for (int p = 0; p < 4; ++p) {
            if (p < 3) { S1_LOAD(p + 1); S1_AF(p + 1, afn); }
            const ushort* bc = (p & 1) ? ldsB : ldsA;
#pragma unroll
            for (int kc = 0; kc < 2; ++kc) {
                bf16x8 bf[8];
#pragma unroll
                for (int nt = 0; nt < 8; ++nt)
                    bf[nt] = *(const bf16x8*)(bc + (wc + nt * 16 + lr) * 72 + kc * 32 + lg * 8);
#pragma unroll
                for (int rt = 0; rt < 2; ++rt)
#pragma unroll
                    for (int nt = 0; nt < 8; ++nt)
                        acc[rt][nt] = __builtin_amdgcn_mfma_f32_16x16x32_bf16(af[rt][kc], bf[nt], acc[rt][nt], 0, 0, 0);
            }
            if (p < 3) { S1_WRITE(((p + 1) & 1) ? ldsB : ldsA); }
            __syncthreads();
            if (p < 3) {
#pragma unroll
                for (int rt = 0; rt < 2; ++rt)
#pragma unroll
                    for (int kc = 0; kc < 2; ++kc) af[rt][kc] = afn[rt][kc];
            }
        }
#pragma unroll
        for (int rt = 0; rt < 2; ++rt)
#pragma unroll
            for (int nt = 0; nt < 8; ++nt) {
                const int col = wc + nt * 16 + lr;
                const float bv = b1[col];
#pragma unroll
                for (int j = 0; j < 4; ++j) {
                    const int hr = wr + rt * 16 + lg * 4 + j;
                    ldsA[hr * 264 + col] = f2b(fmaxf(acc[rt][nt][j] + bv, 0.f));
                }
            }
#undef S1_LOAD
#undef S1_WRITE
#undef S1_AF
    }

    // ======== stage 2 ========
    {
        bf16x8 sreg2[4];
#define S2_LOAD(p)                                                                 \
    _Pragma("unroll")                                                              \
    for (int it = 0; it < 4; ++it)                                                 \
        sreg2[it] = *(const bf16x8*)(w2t + (size_t)(sc0 + it * 32) * 256 + (p) * 64 + sgk);

#define S2_WRITE(half)                                                             \
    _Pragma("unroll")                                                              \
    for (int it = 0; it < 4; ++it)                                                 \
        *(bf16x8*)(ldsB + (half) * (128 * 72) + (sc0 + it * 32) * 72 + sgk) = sreg2[it];

        S2_LOAD(0); S2_WRITE(0);
        __syncthreads();

        const int wr = (wave >> 1) * 32, wc = (wave & 1) * 64;
        f32x4 acc[2][4];
#pragma unroll
        for (int rt = 0; rt < 2; ++rt)
#pragma unroll
            for (int nt = 0; nt < 4; ++nt) acc[rt][nt] = (f32x4){0.f, 0.f, 0.f, 0.f};
        bf16x8 af[2][2];

#pragma unroll
        for (int p = 0; p < 4; ++p) {
            if (p < 3) S2_LOAD(p + 1);
#pragma unroll
            for (int rt = 0; rt < 2; ++rt) {
                const int ar = wr + rt * 16 + lr;
#pragma unroll
                for (int kc = 0; kc < 2; ++kc)
                    af[rt][kc] = *(const bf16x8*)(ldsA + ar * 264 + p * 64 + kc * 32 + lg * 8);
            }
            const ushort* bc = ldsB + (p & 1) * (128 * 72);
#pragma unroll
            for (int kc = 0; kc < 2; ++kc) {
                bf16x8 bf[4];
#pragma unroll
                for (int nt = 0; nt < 4; ++nt)
                    bf[nt] = *(const bf16x8*)(bc + (wc + nt * 16 + lr) * 72 + kc * 32 + lg * 8);
#pragma unroll
                for (int rt = 0; rt < 2; ++rt)
#pragma unroll
                    for (int nt = 0; nt < 4; ++nt)
                        acc[rt][nt] = __builtin_amdgcn_mfma_f32_16x16x32_bf16(af[rt][kc], bf[nt], acc[rt][nt], 0, 0, 0);
            }
            if (p < 3) S2_WRITE((p + 1) & 1);
            __syncthreads();
        }
#pragma unroll
        for (int rt = 0; rt < 2; ++rt)
#pragma unroll
            for (int nt = 0; nt < 4; ++nt) {
                const int col = wc + nt * 16 + lr;
                const float bv = b2[col];
#pragma unroll
                for (int j = 0; j < 4; ++j) {
                    const int r = row0 + wr + rt * 16 + lg * 4 + j;
                    if (r < N_NODES)
                        out[(size_t)r * 128 + col] = acc[rt][nt][j] + bv;
                }
            }
#undef S2_LOAD
#undef S2_WRITE
    }
}

// ---------------- CSR build (counting sort by dst) ----------------

__global__ void zero_cnt(int* __restrict__ cnt) {
    int i = blockIdx.x * 256 + threadIdx.x;
    if (i < NT_PAD) cnt[i] = 0;
}

__global__ void hist_dst(const int* __restrict__ dst, int* __restrict__ cnt) {
    int e = blockIdx.x * 256 + threadIdx.x;
    if (e < N_EDGES) atomicAdd(&cnt[dst[e]], 1);
}

__global__ void scan_tiles(const int* __restrict__ cnt, int* __restrict__ tincl, int* __restrict__ bsum) {
    __shared__ int s[256];
    int i = blockIdx.x * 256 + threadIdx.x;
    int v = cnt[i];
    s[threadIdx.x] = v;
    __syncthreads();
    for (int off = 1; off < 256; off <<= 1) {
        int add = (threadIdx.x >= off) ? s[threadIdx.x - off] : 0;
        __syncthreads();
        s[threadIdx.x] += add;
        __syncthreads();
    }
    tincl[i] = s[threadIdx.x];
    if (threadIdx.x == 255) bsum[blockIdx.x] = s[255];
}

__global__ void scan_bsum(const int* __restrict__ bsum, int* __restrict__ bex) {
    __shared__ int s[256];
    int v = (threadIdx.x < N_TILES) ? bsum[threadIdx.x] : 0;
    s[threadIdx.x] = v;
    __syncthreads();
    for (int off = 1; off < 256; off <<= 1) {
        int add = (threadIdx.x >= off) ? s[threadIdx.x - off] : 0;
        __syncthreads();
        s[threadIdx.x] += add;
        __syncthreads();
    }
    if (threadIdx.x < N_TILES) bex[threadIdx.x] = s[threadIdx.x] - v;
}

__global__ void finalize_base(const int* __restrict__ cnt, const int* __restrict__ tincl,
                              const int* __restrict__ bex, int* __restrict__ base,
                              int* __restrict__ cursor) {
    int i = blockIdx.x * 256 + threadIdx.x;
    int b = tincl[i] - cnt[i] + bex[blockIdx.x];
    base[i] = b; cursor[i] = b;
}

__global__ void scatter_ids(const int* __restrict__ src, const int* __restrict__ dst,
                            const int* __restrict__ et, int* __restrict__ cursor,
                            unsigned* __restrict__ sorted) {
    int e = blockIdx.x * 256 + threadIdx.x;
    if (e >= N_EDGES) return;
    int pos = atomicAdd(&cursor[dst[e]], 1);
    sorted[pos] = ((unsigned)src[e] << 3) | (unsigned)et[e];
}

// ---------------- gather_agg16: 1024 threads, 16 waves = 16 nodes (1 node/wave),
// LDS-staged, coalesced frag-major writeout ----------------

#define ACC_ADD(sd, v)                                                       \
    {                                                                        \
        float lo = asf((v) << 16);                                           \
        float hi = asf((v) & 0xffff0000u);                                   \
        switch ((sd) & 7u) {                                                 \
            case 0: a0[0] += lo; a1[0] += hi; asm volatile(""); break;       \
            case 1: a0[1] += lo; a1[1] += hi; asm volatile(""); break;       \
            case 2: a0[2] += lo; a1[2] += hi; asm volatile(""); break;       \
            case 3: a0[3] += lo; a1[3] += hi; asm volatile(""); break;       \
            case 4: a0[4] += lo; a1[4] += hi; asm volatile(""); break;       \
            case 5: a0[5] += lo; a1[5] += hi; asm volatile(""); break;       \
            case 6: a0[6] += lo; a1[6] += hi; asm volatile(""); break;       \
            default: a0[7] += lo; a1[7] += hi; asm volatile(""); break;      \
        }                                                                    \
    }

__global__ __launch_bounds__(1024) void gather_agg16(
        const unsigned* __restrict__ sorted, const int* __restrict__ base,
        const int* __restrict__ cnt, const ushort* __restrict__ xbf,
        ushort* __restrict__ aggF) {
    __shared__ ushort lds[16 * 1032];        // 33,024 B
    const int t = threadIdx.x;
    const int w = t >> 6, lane = t & 63;     // w = 0..15 = node local
    const int ng = blockIdx.x;               // node group: nodes 16*ng .. 16*ng+15
    const int loff = lane * 2;

    {
        const int nl = w;
        const int n = ng * 16 + nl;
        const int b = base[n], c = cnt[n];

        float a0[8], a1[8];
#pragma unroll
        for (int r = 0; r < 8; ++r) { a0[r] = 0.f; a1[r] = 0.f; }

        const unsigned* sp = sorted + b;
        int i = 0;
        for (; i + 4 <= c; i += 4) {
            unsigned s0 = __builtin_amdgcn_readfirstlane(sp[i]);
            unsigned s1 = __builtin_amdgcn_readfirstlane(sp[i + 1]);
            unsigned s2 = __builtin_amdgcn_readfirstlane(sp[i + 2]);
            unsigned s3 = __builtin_amdgcn_readfirstlane(sp[i + 3]);
            unsigned v0 = *(const unsigned*)(xbf + ((size_t)(s0 >> 3) << 7) + loff);
            unsigned v1 = *(const unsigned*)(xbf + ((size_t)(s1 >> 3) << 7) + loff);
            unsigned v2 = *(const unsigned*)(xbf + ((size_t)(s2 >> 3) << 7) + loff);
            unsigned v3 = *(const unsigned*)(xbf + ((size_t)(s3 >> 3) << 7) + loff);
            ACC_ADD(s0, v0); ACC_ADD(s1, v1); ACC_ADD(s2, v2); ACC_ADD(s3, v3);
        }
        for (; i < c; ++i) {
            unsigned sd = __builtin_amdgcn_readfirstlane(sp[i]);
            unsigned v = *(const unsigned*)(xbf + ((size_t)(sd >> 3) << 7) + loff);
            ACC_ADD(sd, v);
        }
        // stage row-major into LDS (lane writes 4B at consecutive addresses)
#pragma unroll
        for (int r = 0; r < 8; ++r) {
            unsigned pk = (unsigned)f2b(a0[r]) | ((unsigned)f2b(a1[r]) << 16);
            *(unsigned*)(lds + nl * 1032 + r * 128 + loff) = pk;
        }
    }
    __syncthreads();

    // coalesced writeout: 2048 chunks of 16B; cid = p*128 + kcw*64 + flane,
    // flane = lgw*16 + nl; LDS read at [nl][p*64 + kcw*32 + lgw*8].
    const int bq = ng >> 2;
    const int half = (ng & 3) >> 1, rt = ng & 1;
#pragma unroll
    for (int it = 0; it < 2; ++it) {
        int cid = it * 1024 + t;
        int flane = cid & 63, kcw = (cid >> 6) & 1, p = cid >> 7;
        int nl = flane & 15, lgw = flane >> 4;
        bf16x8 v = *(const bf16x8*)(lds + nl * 1032 + p * 64 + kcw * 32 + lgw * 8);
        size_t idx = ((((((size_t)bq * 16 + p) * 2 + half) * 2 + rt) * 2 + kcw) * 64 + flane) * 8;
        *(bf16x8*)(aggF + idx) = v;
    }
}
#undef ACC_ADD

// ---------------- launch ----------------

extern "C" void kernel_launch(void* const* d_in, const int* in_sizes, int n_in,
                              void* d_out, int out_size, void* d_ws, size_t ws_size,
                              hipStream_t stream) {
    const float* x     = (const float*)d_in[0];
    const int*   src   = (const int*)  d_in[1];
    const int*   dst   = (const int*)  d_in[2];
    const int*   etype = (const int*)  d_in[3];
    const float* Wrel  = (const float*)d_in[4];
    const float* Wloop = (const float*)d_in[5];
    const float* brel  = (const float*)d_in[6];
    const float* W1    = (const float*)d_in[7];
    const float* b1    = (const float*)d_in[8];
    const float* W2    = (const float*)d_in[9];
    const float* b2    = (const float*)d_in[10];
    float* out = (float*)d_out;

    // ws layout — total 131,794,688 B (ws_size = 256 MiB, confirmed round 7/8).
    char* ws = (char*)d_ws;
    ushort* aggF  = (ushort*)ws;                     // 102,498,304 B  [782][16][2][2][2][64][8] bf16
    ushort* wt    = (ushort*)(ws + 102498304);       //     491,520 B  wst/w1t/w2t
    char* meta    = ws + 102989824;
    int* cnt      = (int*)(meta);                    // 200,704 B
    int* base     = (int*)(meta + 200704);           // 200,704 B
    int* cursor   = (int*)(meta + 401408);           // 200,704 B
    int* tincl    = (int*)(meta + 602112);           // 200,704 B
    int* bsum     = (int*)(meta + 802816);           //   1,024 B
    int* bex      = (int*)(meta + 803840);           //   1,024 B
    unsigned* sorted = (unsigned*)(meta + 804864);   // 2,400,000 B  (meta end 106,194,688)
    ushort* xbf   = (ushort*)(ws + 106194688);       // 12,800,000 B  bf16(x)
    ushort* midbf = (ushort*)(ws + 118994688);       // 12,800,000 B  bf16(mid)  (end 131,794,688)

    const ushort* wst = wt;              // [128][1152]  stack(Wrel, Wloop)^T
    const ushort* w1t = wt + 147456;     // [256][256]
    const ushort* w2t = wt + 212992;     // [128][256]

    conv_f32_bf16<<<6250, 256, 0, stream>>>(x, xbf);
    transpose_wts3<<<dim3(64, 3), 256, 0, stream>>>(Wloop, Wrel, W1, W2, wt);

    // CSR build (counting sort of edges by dst)
    zero_cnt<<<N_TILES, 256, 0, stream>>>(cnt);
    hist_dst<<<(N_EDGES + 255) / 256, 256, 0, stream>>>(dst, cnt);
    scan_tiles<<<N_TILES, 256, 0, stream>>>(cnt, tincl, bsum);
    scan_bsum<<<1, 256, 0, stream>>>(bsum, bex);
    finalize_base<<<N_TILES, 256, 0, stream>>>(cnt, tincl, bex, base, cursor);
    scatter_ids<<<(N_EDGES + 255) / 256, 256, 0, stream>>>(src, dst, etype, cursor, sorted);

    // aggF (fragment-major) = sum of x[src] over edges (dst, etype); 1 node/wave, coalesced writes
    gather_agg16<<<N_NODES / 16, 1024, 0, stream>>>(sorted, base, cnt, xbf, aggF);

    // midbf = bf16( concat(agg, x) @ stack(Wrel, Wloop) + brel )  (K=1152, 18 phases, coalesced A)
    mfma_gemm<18, 0, 0, 128, 4><<<dim3(NBLK, 1), 256, 0, stream>>>(aggF, xbf, wst, brel, (void*)midbf);

    // out = relu(concat(x, mid) @ W1 + b1) @ W2 + b2   (fused, h in LDS)
    mlp_fused<<<NBLK, 256, 0, stream>>>(xbf, midbf, w1t, w2t, b1, b2, out);
}

// Round 22
// 190.416 us; speedup vs baseline: 1.1745x; 1.0265x over previous
//
#include <hip/hip_runtime.h>

#define N_NODES 50000
#define N_EDGES 600000
#define N_REL 8
#define NT_PAD 50176      // 196 * 256
#define N_TILES 196
#define NBLK 782          // ceil(50000/64)

typedef __attribute__((ext_vector_type(8))) short bf16x8;
typedef __attribute__((ext_vector_type(4))) float f32x4;

__device__ __forceinline__ ushort f2b(float f) {
    union { float f; unsigned u; } v; v.f = f;
    unsigned r = v.u + 0x7FFFu + ((v.u >> 16) & 1u);
    return (ushort)(r >> 16);
}
__device__ __forceinline__ float b2f(ushort s) {
    union { unsigned u; float f; } v; v.u = ((unsigned)s) << 16;
    return v.f;
}
__device__ __forceinline__ float asf(unsigned u) {
    union { unsigned u; float f; } v; v.u = u;
    return v.f;
}

// ---------------- converts / weight prep ----------------

__global__ void conv_f32_bf16(const float* __restrict__ in, ushort* __restrict__ outb) {
    int i = (blockIdx.x * 256 + threadIdx.x) * 4;
    float4 f = *(const float4*)(in + i);
    ushort4 o; o.x = f2b(f.x); o.y = f2b(f.y); o.z = f2b(f.z); o.w = f2b(f.w);
    *(ushort4*)(outb + i) = o;
}

// wst [128 cols][1152 k] = stack(Wrel[0..7], Wloop)^T ; w1t [256][256]; w2t [128][256]
__global__ void transpose_wts3(const float* __restrict__ Wloop, const float* __restrict__ Wrel,
                               const float* __restrict__ W1, const float* __restrict__ W2,
                               ushort* __restrict__ wt) {
    int y = blockIdx.y;
    if (y == 0) {
        for (int idx = blockIdx.x * 256 + threadIdx.x; idx < 128 * 1152; idx += gridDim.x * 256) {
            int c = idx / 1152, kg = idx - c * 1152;
            float v = (kg < 1024) ? Wrel[(size_t)((kg >> 7) * 128 + (kg & 127)) * 128 + c]
                                  : Wloop[(size_t)(kg - 1024) * 128 + c];
            wt[idx] = f2b(v);
        }
    } else if (y == 1) {
        for (int idx = blockIdx.x * 256 + threadIdx.x; idx < 256 * 256; idx += gridDim.x * 256) {
            int c = idx >> 8, k = idx & 255;
            wt[147456 + idx] = f2b(W1[k * 256 + c]);
        }
    } else {
        for (int idx = blockIdx.x * 256 + threadIdx.x; idx < 128 * 256; idx += gridDim.x * 256) {
            int c = idx >> 8, k = idx & 255;
            wt[212992 + idx] = f2b(W2[k * 128 + c]);
        }
    }
}

// ---------------- MFMA GEMM (r19): 64x128 tile, BK=64, dbuf + A-prefetch, frag-major A ----------------
// KMODE 0 (NPH=18): p<16 reads fragment-major aggF (fully coalesced, lane*16B);
//                   p>=16 reads A1 + (p-16)*64 (row-major xbf, stride 128).
// OMODE 4: bf16 out+bias, width 128.
template<int NPH, int KMODE, int AS, int CTOT, int OMODE>
__global__ __launch_bounds__(256, 4) void mfma_gemm(
        const ushort* __restrict__ A0, const ushort* __restrict__ A1,
        const ushort* __restrict__ Bt, const float* __restrict__ bias,
        void* __restrict__ outv) {
    __shared__ ushort bs[2][128 * 72];
    const int t = threadIdx.x;
    const int wave = t >> 6, lane = t & 63;
    const int lr = lane & 15, lg = lane >> 4;
    const int wr = (wave >> 1) * 32, wc = (wave & 1) * 64;
    const int row0 = blockIdx.x * 64;
    const int KTOT = NPH * 64;
    const ushort* Btb = Bt + (size_t)blockIdx.y * 128 * KTOT;
    const int sgk = (t & 7) * 8;
    const int sc0 = t >> 3;

#define STAGE_LOAD(p)                                                              \
    _Pragma("unroll")                                                              \
    for (int it = 0; it < 4; ++it)                                                 \
        sreg[it] = *(const bf16x8*)(Btb + (size_t)(sc0 + it * 32) * KTOT +         \
                                    (p) * 64 + sgk);

#define STAGE_WRITE(b)                                                             \
    _Pragma("unroll")                                                              \
    for (int it = 0; it < 4; ++it)                                                 \
        *(bf16x8*)(&bs[b][(sc0 + it * 32) * 72 + sgk]) = sreg[it];

#define LOAD_AF(p, dstf)                                                           \
    {                                                                              \
        if (KMODE == 0 && (p) < 16) {                                              \
            _Pragma("unroll")                                                      \
            for (int rt = 0; rt < 2; ++rt)                                         \
                _Pragma("unroll")                                                  \
                for (int kc = 0; kc < 2; ++kc)                                     \
                    dstf[rt][kc] = *(const bf16x8*)(A0 +                           \
                        ((((((size_t)blockIdx.x * 16 + (p)) * 2 + (wave >> 1))     \
                           * 2 + rt) * 2 + kc) * 64 + lane) * 8);                  \
        } else {                                                                   \
            const ushort* Ap; int as_;                                             \
            if (KMODE == 0) { Ap = A1 + ((p) - 16) * 64; as_ = 128; }              \
            else            { Ap = A0 + (p) * 64;        as_ = AS;  }              \
            _Pragma("unroll")                                                      \
            for (int rt = 0; rt < 2; ++rt) {                                       \
                int ar = row0 + wr + rt * 16 + lr;                                 \
                if (ar >= N_NODES) ar = 0;                                         \
                _Pragma("unroll")                                                  \
                for (int kc = 0; kc < 2; ++kc)                                     \
                    dstf[rt][kc] = *(const bf16x8*)(Ap + (size_t)ar * as_ + kc * 32 + lg * 8); \
            }                                                                      \
        }                                                                          \
    }

    f32x4 acc[2][4];
#pragma unroll
    for (int rt = 0; rt < 2; ++rt)
#pragma unroll
        for (int nt = 0; nt < 4; ++nt) acc[rt][nt] = (f32x4){0.f, 0.f, 0.f, 0.f};

    bf16x8 af[2][2], afn[2][2], sreg[4];

    STAGE_LOAD(0);
    LOAD_AF(0, af);
    STAGE_WRITE(0);
    __syncthreads();

#pragma unroll
    for (int p = 0; p < NPH; ++p) {
        if (p + 1 < NPH) {
            STAGE_LOAD(p + 1);
            LOAD_AF(p + 1, afn);
        }
        const ushort* bcur = bs[p & 1];
#pragma unroll
        for (int kc = 0; kc < 2; ++kc) {
            bf16x8 bf[4];
#pragma unroll
            for (int nt = 0; nt < 4; ++nt)
                bf[nt] = *(const bf16x8*)(bcur + (wc + nt * 16 + lr) * 72 + kc * 32 + lg * 8);
#pragma unroll
            for (int rt = 0; rt < 2; ++rt)
#pragma unroll
                for (int nt = 0; nt < 4; ++nt)
                    acc[rt][nt] = __builtin_amdgcn_mfma_f32_16x16x32_bf16(af[rt][kc], bf[nt], acc[rt][nt], 0, 0, 0);
        }
        if (p + 1 < NPH) STAGE_WRITE((p + 1) & 1);
        __syncthreads();
        if (p + 1 < NPH) {
#pragma unroll
            for (int rt = 0; rt < 2; ++rt)
#pragma unroll
                for (int kc = 0; kc < 2; ++kc) af[rt][kc] = afn[rt][kc];
        }
    }

    const int colbase = blockIdx.y * 128;
#pragma unroll
    for (int rt = 0; rt < 2; ++rt) {
#pragma unroll
        for (int nt = 0; nt < 4; ++nt) {
            const int col = colbase + wc + nt * 16 + lr;
            const float bv = bias[col];
#pragma unroll
            for (int j = 0; j < 4; ++j) {
                const int r = row0 + wr + rt * 16 + lg * 4 + j;
                if (r >= N_NODES) continue;
                float vv = acc[rt][nt][j] + bv;
                if (OMODE == 0) {
                    ((float*)outv)[(size_t)r * CTOT + col] = vv;
                } else { // OMODE 4
                    ((ushort*)outv)[(size_t)r * 128 + col] = f2b(vv);
                }
            }
        }
    }
#undef STAGE_LOAD
#undef STAGE_WRITE
#undef LOAD_AF
}

// ---------------- fused MLP (r18 proven): h in LDS ----------------
__global__ __launch_bounds__(256, 2) void mlp_fused(
        const ushort* __restrict__ xbf, const ushort* __restrict__ midbf,
        const ushort* __restrict__ w1t, const ushort* __restrict__ w2t,
        const float* __restrict__ b1, const float* __restrict__ b2,
        float* __restrict__ out) {
    __shared__ ushort ldsA[256 * 72];
    __shared__ ushort ldsB[256 * 72];
    const int t = threadIdx.x;
    const int wave = t >> 6, lane = t & 63;
    const int lr = lane & 15, lg = lane >> 4;
    const int row0 = blockIdx.x * 64;
    const int sgk = (t & 7) * 8;
    const int sc0 = t >> 3;

    // ======== stage 1 ========
    {
        const int wr = (wave >> 1) * 32, wc = (wave & 1) * 128;
        f32x4 acc[2][8];
#pragma unroll
        for (int rt = 0; rt < 2; ++rt)
#pragma unroll
            for (int nt = 0; nt < 8; ++nt) acc[rt][nt] = (f32x4){0.f, 0.f, 0.f, 0.f};
        bf16x8 af[2][2], afn[2][2], sreg[8];

#define S1_LOAD(p)                                                                 \
    _Pragma("unroll")                                                              \
    for (int it = 0; it < 8; ++it)                                                 \
        sreg[it] = *(const bf16x8*)(w1t + (size_t)(sc0 + it * 32) * 256 + (p) * 64 + sgk);

#define S1_WRITE(bptr)                                                             \
    _Pragma("unroll")                                                              \
    for (int it = 0; it < 8; ++it)                                                 \
        *(bf16x8*)((bptr) + (sc0 + it * 32) * 72 + sgk) = sreg[it];

#define S1_AF(p, dstf)                                                             \
    {                                                                              \
        const ushort* Ap = ((p) < 2) ? (xbf + (p) * 64) : (midbf + ((p) - 2) * 64);\
        _Pragma("unroll")                                                          \
        for (int rt = 0; rt < 2; ++rt) {                                           \
            int ar = row0 + wr + rt * 16 + lr;                                     \
            if (ar >= N_NODES) ar = 0;                                             \
            _Pragma("unroll")                                                      \
            for (int kc = 0; kc < 2; ++kc)                                         \
                dstf[rt][kc] = *(const bf16x8*)(Ap + (size_t)ar * 128 + kc * 32 + lg * 8); \
        }                                                                          \
    }

        S1_LOAD(0); S1_AF(0, af); S1_WRITE(ldsA);
        __syncthreads();
#pragma unroll
        for (int p = 0; p < 4; ++p) {
            if (p < 3) { S1_LOAD(p + 1); S1_AF(p + 1, afn); }
            const ushort* bc = (p & 1) ? ldsB : ldsA;
#pragma unroll
            for (int kc = 0; kc < 2; ++kc) {
                bf16x8 bf[8];
#pragma unroll
                for (int nt = 0; nt < 8; ++nt)
                    bf[nt] = *(const bf16x8*)(bc + (wc + nt * 16 + lr) * 72 + kc * 32 + lg * 8);
#pragma unroll
                for (int rt = 0; rt < 2; ++rt)
#pragma unroll
                    for (int nt = 0; nt < 8; ++nt)
                        acc[rt][nt] = __builtin_amdgcn_mfma_f32_16x16x32_bf16(af[rt][kc], bf[nt], acc[rt][nt], 0, 0, 0);
            }
            if (p < 3) { S1_WRITE(((p + 1) & 1) ? ldsB : ldsA); }
            __syncthreads();
            if (p < 3) {
#pragma unroll
                for (int rt = 0; rt < 2; ++rt)
#pragma unroll
                    for (int kc = 0; kc < 2; ++kc) af[rt][kc] = afn[rt][kc];
            }
        }
#pragma unroll
        for (int rt = 0; rt < 2; ++rt)
#pragma unroll
            for (int nt = 0; nt < 8; ++nt) {
                const int col = wc + nt * 16 + lr;
                const float bv = b1[col];
#pragma unroll
                for (int j = 0; j < 4; ++j) {
                    const int hr = wr + rt * 16 + lg * 4 + j;
                    ldsA[hr * 264 + col] = f2b(fmaxf(acc[rt][nt][j] + bv, 0.f));
                }
            }
#undef S1_LOAD
#undef S1_WRITE
#undef S1_AF
    }

    // ======== stage 2 ========
    {
        bf16x8 sreg2[4];
#define S2_LOAD(p)                                                                 \
    _Pragma("unroll")                                                              \
    for (int it = 0; it < 4; ++it)                                                 \
        sreg2[it] = *(const bf16x8*)(w2t + (size_t)(sc0 + it * 32) * 256 + (p) * 64 + sgk);

#define S2_WRITE(half)                                                             \
    _Pragma("unroll")                                                              \
    for (int it = 0; it < 4; ++it)                                                 \
        *(bf16x8*)(ldsB + (half) * (128 * 72) + (sc0 + it * 32) * 72 + sgk) = sreg2[it];

        S2_LOAD(0); S2_WRITE(0);
        __syncthreads();

        const int wr = (wave >> 1) * 32, wc = (wave & 1) * 64;
        f32x4 acc[2][4];
#pragma unroll
        for (int rt = 0; rt < 2; ++rt)
#pragma unroll
            for (int nt = 0; nt < 4; ++nt) acc[rt][nt] = (f32x4){0.f, 0.f, 0.f, 0.f};
        bf16x8 af[2][2];

#pragma unroll
        for (int p = 0; p < 4; ++p) {
            if (p < 3) S2_LOAD(p + 1);
#pragma unroll
            for (int rt = 0; rt < 2; ++rt) {
                const int ar = wr + rt * 16 + lr;
#pragma unroll
                for (int kc = 0; kc < 2; ++kc)
                    af[rt][kc] = *(const bf16x8*)(ldsA + ar * 264 + p * 64 + kc * 32 + lg * 8);
            }
            const ushort* bc = ldsB + (p & 1) * (128 * 72);
#pragma unroll
            for (int kc = 0; kc < 2; ++kc) {
                bf16x8 bf[4];
#pragma unroll
                for (int nt = 0; nt < 4; ++nt)
                    bf[nt] = *(const bf16x8*)(bc + (wc + nt * 16 + lr) * 72 + kc * 32 + lg * 8);
#pragma unroll
                for (int rt = 0; rt < 2; ++rt)
#pragma unroll
                    for (int nt = 0; nt < 4; ++nt)
                        acc[rt][nt] = __builtin_amdgcn_mfma_f32_16x16x32_bf16(af[rt][kc], bf[nt], acc[rt][nt], 0, 0, 0);
            }
            if (p < 3) S2_WRITE((p + 1) & 1);
            __syncthreads();
        }
#pragma unroll
        for (int rt = 0; rt < 2; ++rt)
#pragma unroll
            for (int nt = 0; nt < 4; ++nt) {
                const int col = wc + nt * 16 + lr;
                const float bv = b2[col];
#pragma unroll
                for (int j = 0; j < 4; ++j) {
                    const int r = row0 + wr + rt * 16 + lg * 4 + j;
                    if (r < N_NODES)
                        out[(size_t)r * 128 + col] = acc[rt][nt][j] + bv;
                }
            }
#undef S2_LOAD
#undef S2_WRITE
    }
}

// ---------------- CSR build (counting sort by dst) ----------------

__global__ void hist_dst(const int* __restrict__ dst, int* __restrict__ cnt) {
    int e = blockIdx.x * 256 + threadIdx.x;
    if (e < N_EDGES) atomicAdd(&cnt[dst[e]], 1);
}

__global__ void scan_tiles(const int* __restrict__ cnt, int* __restrict__ tincl, int* __restrict__ bsum) {
    __shared__ int s[256];
    int i = blockIdx.x * 256 + threadIdx.x;
    int v = cnt[i];
    s[threadIdx.x] = v;
    __syncthreads();
    for (int off = 1; off < 256; off <<= 1) {
        int add = (threadIdx.x >= off) ? s[threadIdx.x - off] : 0;
        __syncthreads();
        s[threadIdx.x] += add;
        __syncthreads();
    }
    tincl[i] = s[threadIdx.x];
    if (threadIdx.x == 255) bsum[blockIdx.x] = s[255];
}

__global__ void scan_bsum(const int* __restrict__ bsum, int* __restrict__ bex) {
    __shared__ int s[256];
    int v = (threadIdx.x < N_TILES) ? bsum[threadIdx.x] : 0;
    s[threadIdx.x] = v;
    __syncthreads();
    for (int off = 1; off < 256; off <<= 1) {
        int add = (threadIdx.x >= off) ? s[threadIdx.x - off] : 0;
        __syncthreads();
        s[threadIdx.x] += add;
        __syncthreads();
    }
    if (threadIdx.x < N_TILES) bex[threadIdx.x] = s[threadIdx.x] - v;
}

__global__ void finalize_base(const int* __restrict__ cnt, const int* __restrict__ tincl,
                              const int* __restrict__ bex, int* __restrict__ base,
                              int* __restrict__ cursor) {
    int i = blockIdx.x * 256 + threadIdx.x;
    int b = tincl[i] - cnt[i] + bex[blockIdx.x];
    base[i] = b; cursor[i] = b;
}

__global__ void scatter_ids(const int* __restrict__ src, const int* __restrict__ dst,
                            const int* __restrict__ et, int* __restrict__ cursor,
                            unsigned* __restrict__ sorted) {
    int e = blockIdx.x * 256 + threadIdx.x;
    if (e >= N_EDGES) return;
    int pos = atomicAdd(&cursor[dst[e]], 1);
    sorted[pos] = ((unsigned)src[e] << 3) | (unsigned)et[e];
}

// ---------------- gather_agg16: 1024 threads, 1 node/wave, 2-stage software pipeline,
// LDS-staged, coalesced frag-major writeout ----------------

#define ACC_ADD(sd, v)                                                       \
    {                                                                        \
        float lo = asf((v) << 16);                                           \
        float hi = asf((v) & 0xffff0000u);                                   \
        switch ((sd) & 7u) {                                                 \
            case 0: a0[0] += lo; a1[0] += hi; asm volatile(""); break;       \
            case 1: a0[1] += lo; a1[1] += hi; asm volatile(""); break;       \
            case 2: a0[2] += lo; a1[2] += hi; asm volatile(""); break;       \
            case 3: a0[3] += lo; a1[3] += hi; asm volatile(""); break;       \
            case 4: a0[4] += lo; a1[4] += hi; asm volatile(""); break;       \
            case 5: a0[5] += lo; a1[5] += hi; asm volatile(""); break;       \
            case 6: a0[6] += lo; a1[6] += hi; asm volatile(""); break;       \
            default: a0[7] += lo; a1[7] += hi; asm volatile(""); break;      \
        }                                                                    \
    }

__global__ __launch_bounds__(1024) void gather_agg16(
        const unsigned* __restrict__ sorted, const int* __restrict__ base,
        const int* __restrict__ cnt, const ushort* __restrict__ xbf,
        ushort* __restrict__ aggF) {
    __shared__ ushort lds[16 * 1032];        // 33,024 B
    const int t = threadIdx.x;
    const int w = t >> 6, lane = t & 63;     // w = 0..15 = node local
    const int ng = blockIdx.x;               // node group: nodes 16*ng .. 16*ng+15
    const int loff = lane * 2;

    {
        const int nl = w;
        const int n = ng * 16 + nl;
        const int b = base[n], c = cnt[n];

        float a0[8], a1[8];
#pragma unroll
        for (int r = 0; r < 8; ++r) { a0[r] = 0.f; a1[r] = 0.f; }

        const unsigned* sp = sorted + b;
        int i = 0;
        if (c >= 8) {
            // prologue: group 0 descriptors + rows in flight
            unsigned d0 = __builtin_amdgcn_readfirstlane(sp[0]);
            unsigned d1 = __builtin_amdgcn_readfirstlane(sp[1]);
            unsigned d2 = __builtin_amdgcn_readfirstlane(sp[2]);
            unsigned d3 = __builtin_amdgcn_readfirstlane(sp[3]);
            unsigned w0 = *(const unsigned*)(xbf + ((size_t)(d0 >> 3) << 7) + loff);
            unsigned w1 = *(const unsigned*)(xbf + ((size_t)(d1 >> 3) << 7) + loff);
            unsigned w2 = *(const unsigned*)(xbf + ((size_t)(d2 >> 3) << 7) + loff);
            unsigned w3 = *(const unsigned*)(xbf + ((size_t)(d3 >> 3) << 7) + loff);
            for (i = 4; i + 4 <= c; i += 4) {
                // issue next group's loads before consuming the current one
                unsigned e0 = __builtin_amdgcn_readfirstlane(sp[i]);
                unsigned e1 = __builtin_amdgcn_readfirstlane(sp[i + 1]);
                unsigned e2 = __builtin_amdgcn_readfirstlane(sp[i + 2]);
                unsigned e3 = __builtin_amdgcn_readfirstlane(sp[i + 3]);
                unsigned u0 = *(const unsigned*)(xbf + ((size_t)(e0 >> 3) << 7) + loff);
                unsigned u1 = *(const unsigned*)(xbf + ((size_t)(e1 >> 3) << 7) + loff);
                unsigned u2 = *(const unsigned*)(xbf + ((size_t)(e2 >> 3) << 7) + loff);
                unsigned u3 = *(const unsigned*)(xbf + ((size_t)(e3 >> 3) << 7) + loff);
                ACC_ADD(d0, w0); ACC_ADD(d1, w1); ACC_ADD(d2, w2); ACC_ADD(d3, w3);
                d0 = e0; d1 = e1; d2 = e2; d3 = e3;
                w0 = u0; w1 = u1; w2 = u2; w3 = u3;
            }
            // epilogue: last in-flight group
            ACC_ADD(d0, w0); ACC_ADD(d1, w1); ACC_ADD(d2, w2); ACC_ADD(d3, w3);
        } else if (c >= 4) {
            unsigned d0 = __builtin_amdgcn_readfirstlane(sp[0]);
            unsigned d1 = __builtin_amdgcn_readfirstlane(sp[1]);
            unsigned d2 = __builtin_amdgcn_readfirstlane(sp[2]);
            unsigned d3 = __builtin_amdgcn_readfirstlane(sp[3]);
            unsigned w0 = *(const unsigned*)(xbf + ((size_t)(d0 >> 3) << 7) + loff);
            unsigned w1 = *(const unsigned*)(xbf + ((size_t)(d1 >> 3) << 7) + loff);
            unsigned w2 = *(const unsigned*)(xbf + ((size_t)(d2 >> 3) << 7) + loff);
            unsigned w3 = *(const unsigned*)(xbf + ((size_t)(d3 >> 3) << 7) + loff);
            ACC_ADD(d0, w0); ACC_ADD(d1, w1); ACC_ADD(d2, w2); ACC_ADD(d3, w3);
            i = 4;
        }
        for (; i < c; ++i) {
            unsigned sd = __builtin_amdgcn_readfirstlane(sp[i]);
            unsigned v = *(const unsigned*)(xbf + ((size_t)(sd >> 3) << 7) + loff);
            ACC_ADD(sd, v);
        }
        // stage row-major into LDS (lane writes 4B at consecutive addresses)
#pragma unroll
        for (int r = 0; r < 8; ++r) {
            unsigned pk = (unsigned)f2b(a0[r]) | ((unsigned)f2b(a1[r]) << 16);
            *(unsigned*)(lds + nl * 1032 + r * 128 + loff) = pk;
        }
    }
    __syncthreads();

    // coalesced writeout: 2048 chunks of 16B; cid = p*128 + kcw*64 + flane,
    // flane = lgw*16 + nl; LDS read at [nl][p*64 + kcw*32 + lgw*8].
    const int bq = ng >> 2;
    const int half = (ng & 3) >> 1, rt = ng & 1;
#pragma unroll
    for (int it = 0; it < 2; ++it) {
        int cid = it * 1024 + t;
        int flane = cid & 63, kcw = (cid >> 6) & 1, p = cid >> 7;
        int nl = flane & 15, lgw = flane >> 4;
        bf16x8 v = *(const bf16x8*)(lds + nl * 1032 + p * 64 + kcw * 32 + lgw * 8);
        size_t idx = ((((((size_t)bq * 16 + p) * 2 + half) * 2 + rt) * 2 + kcw) * 64 + flane) * 8;
        *(bf16x8*)(aggF + idx) = v;
    }
}
#undef ACC_ADD

// ---------------- launch ----------------

extern "C" void kernel_launch(void* const* d_in, const int* in_sizes, int n_in,
                              void* d_out, int out_size, void* d_ws, size_t ws_size,
                              hipStream_t stream) {
    const float* x     = (const float*)d_in[0];
    const int*   src   = (const int*)  d_in[1];
    const int*   dst   = (const int*)  d_in[2];
    const int*   etype = (const int*)  d_in[3];
    const float* Wrel  = (const float*)d_in[4];
    const float* Wloop = (const float*)d_in[5];
    const float* brel  = (const float*)d_in[6];
    const float* W1    = (const float*)d_in[7];
    const float* b1    = (const float*)d_in[8];
    const float* W2    = (const float*)d_in[9];
    const float* b2    = (const float*)d_in[10];
    float* out = (float*)d_out;

    // ws layout — total 131,794,688 B (ws_size = 256 MiB, confirmed round 7/8).
    char* ws = (char*)d_ws;
    ushort* aggF  = (ushort*)ws;                     // 102,498,304 B  [782][16][2][2][2][64][8] bf16
    ushort* wt    = (ushort*)(ws + 102498304);       //     491,520 B  wst/w1t/w2t
    char* meta    = ws + 102989824;
    int* cnt      = (int*)(meta);                    // 200,704 B
    int* base     = (int*)(meta + 200704);           // 200,704 B
    int* cursor   = (int*)(meta + 401408);           // 200,704 B
    int* tincl    = (int*)(meta + 602112);           // 200,704 B
    int* bsum     = (int*)(meta + 802816);           //   1,024 B
    int* bex      = (int*)(meta + 803840);           //   1,024 B
    unsigned* sorted = (unsigned*)(meta + 804864);   // 2,400,000 B  (meta end 106,194,688)
    ushort* xbf   = (ushort*)(ws + 106194688);       // 12,800,000 B  bf16(x)
    ushort* midbf = (ushort*)(ws + 118994688);       // 12,800,000 B  bf16(mid)  (end 131,794,688)

    const ushort* wst = wt;              // [128][1152]  stack(Wrel, Wloop)^T
    const ushort* w1t = wt + 147456;     // [256][256]
    const ushort* w2t = wt + 212992;     // [128][256]

    conv_f32_bf16<<<6250, 256, 0, stream>>>(x, xbf);
    transpose_wts3<<<dim3(64, 3), 256, 0, stream>>>(Wloop, Wrel, W1, W2, wt);

    // CSR build (counting sort of edges by dst); zero via async memset (graph-capturable)
    hipMemsetAsync(cnt, 0, NT_PAD * sizeof(int), stream);
    hist_dst<<<(N_EDGES + 255) / 256, 256, 0, stream>>>(dst, cnt);
    scan_tiles<<<N_TILES, 256, 0, stream>>>(cnt, tincl, bsum);
    scan_bsum<<<1, 256, 0, stream>>>(bsum, bex);
    finalize_base<<<N_TILES, 256, 0, stream>>>(cnt, tincl, bex, base, cursor);
    scatter_ids<<<(N_EDGES + 255) / 256, 256, 0, stream>>>(src, dst, etype, cursor, sorted);

    // aggF (fragment-major) = sum of x[src] over edges (dst, etype); 1 node/wave, pipelined
    gather_agg16<<<N_NODES / 16, 1024, 0, stream>>>(sorted, base, cnt, xbf, aggF);

    // midbf = bf16( concat(agg, x) @ stack(Wrel, Wloop) + brel )  (K=1152, 18 phases, coalesced A)
    mfma_gemm<18, 0, 0, 128, 4><<<dim3(NBLK, 1), 256, 0, stream>>>(aggF, xbf, wst, brel, (void*)midbf);

    // out = relu(concat(x, mid) @ W1 + b1) @ W2 + b2   (fused, h in LDS)
    mlp_fused<<<NBLK, 256, 0, stream>>>(xbf, midbf, w1t, w2t, b1, b2, out);
}